// Round 1
// 288.895 us; speedup vs baseline: 1.2021x; 1.2021x over previous
//
#include <hip/hip_runtime.h>
#include <hip/hip_bf16.h>
#include <cstdint>

// Problem constants
#define B_   4
#define S_   2048
#define SP_  2064        // S + 16 pad rows (pad rows: x == 0 -> bias-only qkv)
#define D_   1024
#define H_   16
#define MTOT (B_ * SP_)  // 8256 rows

// q is pre-scaled by 0.125 * log2(e) so softmax = exp2(q'.k) directly
#define QSCALE 0.18033688011112042f

typedef __attribute__((ext_vector_type(8))) short short8;
typedef __attribute__((ext_vector_type(4))) float floatx4;
typedef __attribute__((ext_vector_type(16))) float floatx16;
typedef __attribute__((ext_vector_type(2))) unsigned int uint2v;
typedef __attribute__((ext_vector_type(4))) unsigned int uintx4;

// fp32 -> bf16 round-to-nearest-even
static __device__ inline unsigned short f2b(float f) {
  unsigned u = __builtin_bit_cast(unsigned, f);
  u += 0x7FFFu + ((u >> 16) & 1u);
  return (unsigned short)(u >> 16);
}

// pack two fp32 -> bf16x2 word (round-half-away, same as previous ps path)
static __device__ inline unsigned pk2(float a, float b) {
  unsigned ua = __builtin_bit_cast(unsigned, a) + 0x8000u;
  unsigned ub = __builtin_bit_cast(unsigned, b) + 0x8000u;
  return (ua >> 16) | (ub & 0xFFFF0000u);
}

// async global->LDS, 16 B per lane, dest = wave-uniform base + lane*16
static __device__ inline void gl_lds16(const unsigned short* g, unsigned short* l) {
  __builtin_amdgcn_global_load_lds((__attribute__((address_space(1))) void*)(g),
                                   (__attribute__((address_space(3))) void*)(l),
                                   16, 0, 0);
}

// ---------------------------------------------------------------------------
// Pre-pass 1: cast x (fp32) -> bf16.
// ---------------------------------------------------------------------------
__global__ __launch_bounds__(256) void cast_x(
    const float* __restrict__ x, unsigned short* __restrict__ xh)
{
  const int idx = (blockIdx.x * 256 + threadIdx.x) * 4;  // grid sized exactly
  float4 v = *(const float4*)(x + idx);
  ushort4 h;
  h.x = f2b(v.x); h.y = f2b(v.y); h.z = f2b(v.z); h.w = f2b(v.w);
  *(ushort4*)(xh + idx) = h;
}

// ---------------------------------------------------------------------------
// Pre-pass 2: transpose weight [1024][N] fp32 -> T [N][1024] bf16.
// ---------------------------------------------------------------------------
__global__ __launch_bounds__(256) void wcast_t(
    const float* __restrict__ W, int N, unsigned short* __restrict__ T)
{
  __shared__ float tl[32][33];
  const int t  = threadIdx.x;
  const int n0 = blockIdx.x * 32;
  const int k0 = blockIdx.y * 32;
  const int r  = t >> 3;
  const int c  = (t & 7) * 4;

  float4 w = *(const float4*)(W + (size_t)(k0 + r) * N + n0 + c);
  tl[r][c + 0] = w.x; tl[r][c + 1] = w.y; tl[r][c + 2] = w.z; tl[r][c + 3] = w.w;
  __syncthreads();

  ushort4 h;
  h.x = f2b(tl[c + 0][r]); h.y = f2b(tl[c + 1][r]);
  h.z = f2b(tl[c + 2][r]); h.w = f2b(tl[c + 3][r]);
  *(ushort4*)(T + (size_t)(n0 + r) * 1024 + k0 + c) = h;
}

// ---------------------------------------------------------------------------
// Plain-bf16 MFMA CSS GEMM with LDS-staged coalesced epilogue.
// (unchanged from previous verified version)
// ---------------------------------------------------------------------------
struct SMem {
  unsigned short A[128][40];      // [m][k]
  unsigned short Bm[2][128][40];  // [Wh,Gh][n][k]
  unsigned short spare[2048];     // pad so epilogue Os[128][136] (34816 B) fits
};

template <int MODE>
__global__ __launch_bounds__(256, 2) void css_mfma(
    const unsigned short* __restrict__ xh,
    const unsigned short* __restrict__ w2a, const float* __restrict__ ba,
    const float* __restrict__ ca, unsigned short* __restrict__ oa, float scla,
    const unsigned short* __restrict__ w2b, const float* __restrict__ bb,
    const float* __restrict__ cb, unsigned short* __restrict__ ob, float sclb,
    int N)
{
  __shared__ SMem sm;

  const int t  = threadIdx.x;
  const int m0 = blockIdx.y << 7;

  int sel, n0;
  if (MODE == 0) { sel = blockIdx.x >> 1; n0 = (blockIdx.x & 1) << 7; }
  else           { sel = 0;               n0 = blockIdx.x << 7; }

  const unsigned short* w2   = sel ? w2b : w2a;
  const float*          bias = sel ? bb  : ba;
  const float*          bisc = sel ? cb  : ca;
  unsigned short*       outp = sel ? ob  : oa;
  const float           scl  = sel ? sclb : scla;

  // staging: 2 threads per row, 16 shorts each (2 uint4 per buffer per thread)
  const int srow = t >> 1;
  const int koff = (t & 1) << 4;

  const int grow = m0 + srow;
  const int bb0  = grow / SP_;
  const int ss0  = grow - bb0 * SP_;
  const bool avalid = (grow < MTOT) && (ss0 < S_);
  const size_t aoff = (size_t)(bb0 * S_ + ss0) * D_ + koff;
  const size_t boff = (size_t)(n0 + srow) * D_ + koff;
  const size_t mstride = (size_t)N * D_;

  const int lane = t & 63;
  const int w    = t >> 6;
  const int lo   = lane & 15;
  const int hi   = lane >> 4;
  const int wm   = (w & 1) << 6;
  const int wn   = (w >> 1) << 6;

  floatx4 lin[4][4], gat[4][4];
#pragma unroll
  for (int i = 0; i < 4; ++i)
#pragma unroll
    for (int j = 0; j < 4; ++j) {
      lin[i][j] = (floatx4){0.f, 0.f, 0.f, 0.f};
      gat[i][j] = (floatx4){0.f, 0.f, 0.f, 0.f};
    }

  uint4 ra0, ra1, rb00, rb01, rb10, rb11;
  const uint4 z4 = make_uint4(0, 0, 0, 0);

  // preload k-chunk 0
  if (avalid) {
    ra0 = *(const uint4*)(xh + aoff);
    ra1 = *(const uint4*)(xh + aoff + 8);
  } else { ra0 = z4; ra1 = z4; }
  rb00 = *(const uint4*)(w2 + boff);
  rb01 = *(const uint4*)(w2 + boff + 8);
  rb10 = *(const uint4*)(w2 + mstride + boff);
  rb11 = *(const uint4*)(w2 + mstride + boff + 8);

  for (int kt = 0; kt < 32; ++kt) {
    __syncthreads();
    *(uint4*)&sm.A[srow][koff]          = ra0;
    *(uint4*)&sm.A[srow][koff + 8]      = ra1;
    *(uint4*)&sm.Bm[0][srow][koff]      = rb00;
    *(uint4*)&sm.Bm[0][srow][koff + 8]  = rb01;
    *(uint4*)&sm.Bm[1][srow][koff]      = rb10;
    *(uint4*)&sm.Bm[1][srow][koff + 8]  = rb11;
    __syncthreads();

    if (kt < 31) {
      const size_t k1 = (size_t)(kt + 1) * 32;
      if (avalid) {
        ra0 = *(const uint4*)(xh + aoff + k1);
        ra1 = *(const uint4*)(xh + aoff + k1 + 8);
      }
      rb00 = *(const uint4*)(w2 + boff + k1);
      rb01 = *(const uint4*)(w2 + boff + k1 + 8);
      rb10 = *(const uint4*)(w2 + mstride + boff + k1);
      rb11 = *(const uint4*)(w2 + mstride + boff + k1 + 8);
    }

    short8 ah[4];
#pragma unroll
    for (int i = 0; i < 4; ++i)
      ah[i] = *(const short8*)&sm.A[wm + i * 16 + lo][hi * 8];
#pragma unroll
    for (int j = 0; j < 4; ++j) {
      const int col = wn + j * 16 + lo;
      short8 bh = *(const short8*)&sm.Bm[0][col][hi * 8];
      short8 gh = *(const short8*)&sm.Bm[1][col][hi * 8];
#pragma unroll
      for (int i = 0; i < 4; ++i) {
        lin[i][j] = __builtin_amdgcn_mfma_f32_16x16x32_bf16(ah[i], bh, lin[i][j], 0, 0, 0);
        gat[i][j] = __builtin_amdgcn_mfma_f32_16x16x32_bf16(ah[i], gh, gat[i][j], 0, 0, 0);
      }
    }
  }

  // ---- epilogue: stage bf16 tile in LDS, then coalesced 16 B stores
  __syncthreads();  // K-loop LDS reads done
  unsigned short (*Os)[136] = reinterpret_cast<unsigned short (*)[136]>(&sm);

#pragma unroll
  for (int j = 0; j < 4; ++j) {
    const int nl = wn + j * 16 + lo;
    const int n  = n0 + nl;
    const float bj = bias[n];
    const float cj = bisc[n];
#pragma unroll
    for (int i = 0; i < 4; ++i) {
      const int ml = wm + i * 16 + (hi << 2);
      unsigned short o16[4];
#pragma unroll
      for (int r = 0; r < 4; ++r) {
        float lv = lin[i][j][r] + bj;
        float gv = gat[i][j][r] + cj;
        o16[r] = f2b(scl * lv / (1.f + __expf(-gv)));
      }
      if (MODE == 0) {
#pragma unroll
        for (int r = 0; r < 4; ++r) Os[ml + r][nl] = o16[r];
      } else {
        *(ushort4*)&Os[nl][ml] = make_ushort4(o16[0], o16[1], o16[2], o16[3]);
      }
    }
  }
  __syncthreads();

  // coalesced store: 16 consecutive lanes cover one 256 B row-run
#pragma unroll
  for (int c = 0; c < 8; ++c) {
    const int rr = (t >> 4) + 16 * c;   // Os row
    const int cc = (t & 15) << 3;       // Os col chunk (8 shorts = 16 B)
    uint4 val = *(const uint4*)&Os[rr][cc];
    if (MODE == 0) {
      const int gm = m0 + rr;
      if (gm < MTOT)
        *(uint4*)(outp + (size_t)gm * N + n0 + cc) = val;
    } else {
      const int g = m0 + cc;            // 8-aligned; SP_ % 8 == 0 so no straddle
      if (g < MTOT) {
        const int vb = g / SP_;
        const int vs = g - vb * SP_;
        *(uint4*)(outp + (size_t)(vb * 1024 + n0 + rr) * SP_ + vs) = val;
      }
    }
  }
}

// ---------------------------------------------------------------------------
// MFMA flash attention v2: swapped 32x32x16 QK^T + fully in-register softmax.
//
//  * QK^T computed as mfma(K, Q) (A = 32 keys x kdim16, B = kdim16 x 32
//    queries, K-dim = 16 exactly -> no wasted half-K). C-layout gives each
//    lane P[q = lane&31][key = (r&3)+8*(r>>2)+4*(lane>>5)] -- the P row is
//    lane-local.
//  * p = exp2(s) (flat softmax: |s| small & shift-invariant, no max pass),
//    packed to bf16 pairs in-register, then 4x permlane32_swap assembles the
//    PV A-fragments directly (keys 8h+j per lane). NO LDS round trip for P
//    -> the 18M-cycle ds_write_b16 bank-conflict path is gone.
//  * Row sums: in-lane 15-add tree per chunk (P is lane-local), one
//    shfl_xor(32) combine at the end; 1/l transposed into the C-layout with
//    16 bpermutes in the epilogue. The per-tile ones-MFMAs are gone.
//  * K/V tiles double-buffered via global_load_lds width=16 with linear LDS
//    dest + inverse-swizzled global source (V: granule ^ (d&7)) so all b128
//    LDS reads spread evenly over the 8 bank groups. One barrier per 64-key
//    tile.
//  * 32 queries/wave, 128/block; grid 1024 = exactly 4 blocks/CU.
// ---------------------------------------------------------------------------
__global__ __launch_bounds__(256, 4) void attn_mfma(
    const unsigned short* __restrict__ Q,   // bf16 [MTOT][256], pre-scaled
    const unsigned short* __restrict__ K,   // bf16 [MTOT][256]
    const unsigned short* __restrict__ VT,  // bf16 [B*1024][SP_]
    float* __restrict__ out)                // fp32 [B][S_][1024]
{
  const int bx = blockIdx.x;
  const int qt = bx & 15;
  const int h  = (bx >> 4) & 15;
  const int b  = bx >> 8;

  const int tid  = threadIdx.x;
  const int lane = tid & 63;
  const int w    = tid >> 6;
  const int l31  = lane & 31;
  const int h32  = lane >> 5;

  const int kbase = b * SP_;        // row base into Q/K
  const int hoff  = h << 4;         // head col offset (shorts)
  const int vbase = (b << 10) + (h << 6);  // row base into VT
  const int q0    = (qt << 7) + (w << 5);  // this wave's first query

  __shared__ __align__(16) unsigned short ksb[2][64 * 16];  // [key][kdim]
  __shared__ __align__(16) unsigned short vsb[2][512 * 8];  // [d][granule^],
                                                            // granule = 8 keys

  // Q B-frag: B[kd = 8*h32 + j][q = l31]  (16 B contiguous per lane)
  const short8 aq =
      *(const short8*)(Q + ((size_t)(kbase + q0 + l31) << 8) + hoff + (h32 << 3));

  floatx16 z16;
#pragma unroll
  for (int r = 0; r < 16; ++r) z16[r] = 0.f;
  floatx16 Of0 = z16, Of1 = z16;
  float lsum = 0.f;

  auto stage = [&](int kt, int sel) {
    const int j0 = kt << 6;
    // K tile: 64 keys x 16 kdims, linear dest = tid*16 B (tid<128)
    if (tid < 128) {
      int kr = j0 + (tid >> 1);
      if (kr >= SP_) kr = 0;  // clamp; masked via p=0 in tail chunk
      gl_lds16(K + ((size_t)(kbase + kr) << 8) + hoff + ((tid & 1) << 3),
               &ksb[sel][tid << 3]);
    }
    // V tile: 64 d-rows x 64 keys; dest linear, source inverse-swizzled so
    // stored granule g' holds keys (g'^(d&7))*8.. -> conflict-even b128 reads
#pragma unroll
    for (int pp = 0; pp < 2; ++pp) {
      const int gi = (pp << 8) + tid;
      const int d  = gi >> 3;
      int koff = j0 + (((gi & 7) ^ (d & 7)) << 3);
      if (koff > SP_ - 8) koff = SP_ - 8;  // tail clamp (data masked by p=0)
      gl_lds16(VT + (size_t)(vbase + d) * SP_ + koff, &vsb[sel][gi << 3]);
    }
  };

  auto chunk = [&](int c, bool tail8, int sel) {
    // A-frag: K[key = c*32 + l31][kd = 8*h32 + j]
    const short8 ak =
        *(const short8*)&ksb[sel][(((c << 5) + l31) << 4) + (h32 << 3)];
    // sc[r] = S^T[key = crow(r,h32)][q = l31]
    floatx16 sc = __builtin_amdgcn_mfma_f32_32x32x16_bf16(ak, aq, z16, 0, 0, 0);

    float p[16];
#pragma unroll
    for (int r = 0; r < 16; ++r) {
      float e = __builtin_amdgcn_exp2f(sc[r]);
      p[r] = (tail8 && r >= 8) ? 0.f : e;   // tail: crow>=16 invalid
    }
    lsum += (((p[0] + p[1]) + (p[2] + p[3])) + ((p[4] + p[5]) + (p[6] + p[7]))) +
            (((p[8] + p[9]) + (p[10] + p[11])) + ((p[12] + p[13]) + (p[14] + p[15])));

    // pack bf16 pairs; word m holds keys (crow(2m,h), crow(2m+1,h))
    const unsigned w0 = pk2(p[0], p[1]),   w1 = pk2(p[2], p[3]);
    const unsigned w2 = pk2(p[4], p[5]),   w3 = pk2(p[6], p[7]);
    const unsigned w4 = pk2(p[8], p[9]),   w5 = pk2(p[10], p[11]);
    const unsigned w6 = pk2(p[12], p[13]), w7 = pk2(p[14], p[15]);

    // permlane32_swap: out0 = {in0.lo | in1.lo->hi}, out1 = {in0.hi->lo | in1.hi}
    const uint2v a02 = __builtin_amdgcn_permlane32_swap(w0, w2, false, false);
    const uint2v a13 = __builtin_amdgcn_permlane32_swap(w1, w3, false, false);
    const uint2v a46 = __builtin_amdgcn_permlane32_swap(w4, w6, false, false);
    const uint2v a57 = __builtin_amdgcn_permlane32_swap(w5, w7, false, false);

    // PA frags: A[q = l31][key = kc*16 + 8*h32 + j]
    const short8 pa0 = __builtin_bit_cast(short8, (uintx4){a02[0], a13[0], a02[1], a13[1]});
    const short8 pa1 = __builtin_bit_cast(short8, (uintx4){a46[0], a57[0], a46[1], a57[1]});

#pragma unroll
    for (int dt = 0; dt < 2; ++dt) {
      const int dl = (dt << 5) + l31;
      const int rb = dl << 6;
      const int sw = dl & 7;
      // B-frag: V[key = c*32 + kc*16 + 8*h32 + j][d = dl], granule ^ (d&7)
      const short8 bv0 =
          *(const short8*)&vsb[sel][rb + ((((c << 2) + 0 + h32) ^ sw) << 3)];
      const short8 bv1 =
          *(const short8*)&vsb[sel][rb + ((((c << 2) + 2 + h32) ^ sw) << 3)];
      floatx16& O = dt ? Of1 : Of0;
      O = __builtin_amdgcn_mfma_f32_32x32x16_bf16(pa0, bv0, O, 0, 0, 0);
      O = __builtin_amdgcn_mfma_f32_32x32x16_bf16(pa1, bv1, O, 0, 0, 0);
    }
  };

  // 2-phase pipeline: stage(t+1) in flight while computing tile t;
  // __syncthreads() drains vmcnt+lgkmcnt once per 64-key tile.
  stage(0, 0);
  __syncthreads();
  for (int kt = 0; kt < 32; ++kt) {
    const int sel = kt & 1;
    stage(kt + 1, sel ^ 1);
    chunk(0, false, sel);
    chunk(1, false, sel);
    __syncthreads();
  }
  chunk(0, true, 0);  // tail tile (keys 2048..2063 valid)

  // epilogue: out[b][q][h*64 + d] = Of / l
  lsum += __shfl_xor(lsum, 32);   // combine the two key-half partial sums
  const float inv = 1.f / lsum;   // per q = l31, replicated across halves
#pragma unroll
  for (int r = 0; r < 16; ++r) {
    const int cr = (r & 3) + ((r >> 2) << 3) + (h32 << 2);  // crow(r,h32)
    const float invr = __shfl(inv, cr);   // transpose 1/l into C-layout
    const int qg = q0 + cr;
    float* op = out + (((size_t)(b * S_ + qg)) << 10) + (h << 6) + l31;
    op[0]  = Of0[r] * invr;
    op[32] = Of1[r] * invr;
  }
}

// ---------------------------------------------------------------------------
extern "C" void kernel_launch(void* const* d_in, const int* in_sizes, int n_in,
                              void* d_out, int out_size, void* d_ws, size_t ws_size,
                              hipStream_t stream) {
  (void)in_sizes; (void)n_in; (void)out_size; (void)ws_size;

  const float* x   = (const float*)d_in[0];
  const float* Wq  = (const float*)d_in[1];
  const float* bq  = (const float*)d_in[2];
  const float* Wqc = (const float*)d_in[3];
  const float* bqc = (const float*)d_in[4];
  const float* Wk  = (const float*)d_in[5];
  const float* bk  = (const float*)d_in[6];
  const float* Wkc = (const float*)d_in[7];
  const float* bkc = (const float*)d_in[8];
  const float* Wv  = (const float*)d_in[9];
  const float* bv  = (const float*)d_in[10];
  const float* Wvc = (const float*)d_in[11];
  const float* bvc = (const float*)d_in[12];
  float* out = (float*)d_out;

  // workspace layout (ushort units), total ~48 MB
  unsigned short* qb  = (unsigned short*)d_ws;
  unsigned short* kbf = qb  + (size_t)MTOT * 256;
  unsigned short* vt  = kbf + (size_t)MTOT * 256;
  unsigned short* xh  = vt  + (size_t)B_ * 1024 * SP_;
  unsigned short* wq2 = xh  + (size_t)B_ * S_ * D_;          // [2][256][1024]
  unsigned short* wk2 = wq2 + (size_t)2 * 256 * 1024;
  unsigned short* wv2 = wk2 + (size_t)2 * 256 * 1024;        // [2][1024][1024]

  dim3 blk(256);
  cast_x<<<(B_ * S_ * D_) / 1024, blk, 0, stream>>>(x, xh);

  wcast_t<<<dim3(8, 32),  blk, 0, stream>>>(Wq,   256, wq2);
  wcast_t<<<dim3(8, 32),  blk, 0, stream>>>(Wqc,  256, wq2 + 256 * 1024);
  wcast_t<<<dim3(8, 32),  blk, 0, stream>>>(Wk,   256, wk2);
  wcast_t<<<dim3(8, 32),  blk, 0, stream>>>(Wkc,  256, wk2 + 256 * 1024);
  wcast_t<<<dim3(32, 32), blk, 0, stream>>>(Wv,  1024, wv2);
  wcast_t<<<dim3(32, 32), blk, 0, stream>>>(Wvc, 1024, wv2 + 1024 * 1024);

  // merged q+k dispatch (grid.x: 0,1 -> q tiles; 2,3 -> k tiles)
  // q output pre-scaled by 0.125*log2e so attention can use exp2 directly
  css_mfma<0><<<dim3(4, 65), blk, 0, stream>>>(xh, wq2, bq, bqc, qb, QSCALE,
                                               wk2, bk, bkc, kbf, 1.0f, 256);
  css_mfma<1><<<dim3(8, 65), blk, 0, stream>>>(xh, wv2, bv, bvc, vt, 1.0f,
                                               wv2, bv, bvc, vt, 1.0f, 1024);

  attn_mfma<<<B_ * H_ * (S_ / 128), blk, 0, stream>>>(qb, kbf, vt, out);
}

// Round 2
// 258.545 us; speedup vs baseline: 1.3432x; 1.1174x over previous
//
#include <hip/hip_runtime.h>
#include <hip/hip_bf16.h>
#include <cstdint>

// Problem constants
#define B_   4
#define S_   2048
#define SP_  2064        // S + 16 pad rows (pad rows: x == 0 -> bias-only qkv)
#define D_   1024
#define H_   16
#define MTOT (B_ * SP_)  // 8256 rows

// q is pre-scaled by 0.125 * log2(e) so softmax = exp2(q'.k) directly
#define QSCALE 0.18033688011112042f

typedef __attribute__((ext_vector_type(8))) short short8;
typedef __attribute__((ext_vector_type(4))) float floatx4;
typedef __attribute__((ext_vector_type(16))) float floatx16;
typedef __attribute__((ext_vector_type(2))) unsigned int uint2v;
typedef __attribute__((ext_vector_type(4))) unsigned int uintx4;

// fp32 -> bf16 round-to-nearest-even
static __device__ inline unsigned short f2b(float f) {
  unsigned u = __builtin_bit_cast(unsigned, f);
  u += 0x7FFFu + ((u >> 16) & 1u);
  return (unsigned short)(u >> 16);
}

// pack two fp32 -> bf16x2 word (round-half-away)
static __device__ inline unsigned pk2(float a, float b) {
  unsigned ua = __builtin_bit_cast(unsigned, a) + 0x8000u;
  unsigned ub = __builtin_bit_cast(unsigned, b) + 0x8000u;
  return (ua >> 16) | (ub & 0xFFFF0000u);
}

// async global->LDS, 16 B per lane, dest = wave-uniform base + lane*16
static __device__ inline void gl_lds16(const unsigned short* g, unsigned short* l) {
  __builtin_amdgcn_global_load_lds((__attribute__((address_space(1))) void*)(g),
                                   (__attribute__((address_space(3))) void*)(l),
                                   16, 0, 0);
}

// ---------------------------------------------------------------------------
// Pre-pass 1: cast x (fp32) -> bf16.
// ---------------------------------------------------------------------------
__global__ __launch_bounds__(256) void cast_x(
    const float* __restrict__ x, unsigned short* __restrict__ xh)
{
  const int idx = (blockIdx.x * 256 + threadIdx.x) * 4;  // grid sized exactly
  float4 v = *(const float4*)(x + idx);
  ushort4 h;
  h.x = f2b(v.x); h.y = f2b(v.y); h.z = f2b(v.z); h.w = f2b(v.w);
  *(ushort4*)(xh + idx) = h;
}

// ---------------------------------------------------------------------------
// Pre-pass 2: transpose weight [1024][N] fp32 -> T [N][1024] bf16.
// ---------------------------------------------------------------------------
__global__ __launch_bounds__(256) void wcast_t(
    const float* __restrict__ W, int N, unsigned short* __restrict__ T)
{
  __shared__ float tl[32][33];
  const int t  = threadIdx.x;
  const int n0 = blockIdx.x * 32;
  const int k0 = blockIdx.y * 32;
  const int r  = t >> 3;
  const int c  = (t & 7) * 4;

  float4 w = *(const float4*)(W + (size_t)(k0 + r) * N + n0 + c);
  tl[r][c + 0] = w.x; tl[r][c + 1] = w.y; tl[r][c + 2] = w.z; tl[r][c + 3] = w.w;
  __syncthreads();

  ushort4 h;
  h.x = f2b(tl[c + 0][r]); h.y = f2b(tl[c + 1][r]);
  h.z = f2b(tl[c + 2][r]); h.w = f2b(tl[c + 3][r]);
  *(ushort4*)(T + (size_t)(n0 + r) * 1024 + k0 + c) = h;
}

// ---------------------------------------------------------------------------
// Merged CSS GEMM (q + k + v in ONE dispatch), m97-class structure:
//  * global_load_lds width=16 staging (no VGPR round-trip, no ds_writes)
//  * double-buffered LDS, stage(t+1) issued BEFORE compute(t), ONE barrier
//    per K-step -> HBM/L2 latency of the stage hides under 32 MFMAs
//  * grid (12, 65) = 780 blocks: nt 0-1 -> q, 2-3 -> k, 4-11 -> v
//  * pad rows (grow % SP_ >= S_) stage dummy data (row 0) and are overridden
//    in the epilogue with the exact bias-only value scl*b*sigmoid(c), which
//    is what x=0 produces; rows >= MTOT are never stored.
// LDS: 2 x (A[128][32] + B0[128][32] + B1[128][32]) = 48 KiB, epilogue
// Os[128][136] (34816 B) overlays the same buffer.
// ---------------------------------------------------------------------------
__global__ __launch_bounds__(256, 2) void css_mfma2(
    const unsigned short* __restrict__ xh,
    const unsigned short* __restrict__ wq2, const float* __restrict__ bq,
    const float* __restrict__ bqc,
    const unsigned short* __restrict__ wk2, const float* __restrict__ bk,
    const float* __restrict__ bkc,
    const unsigned short* __restrict__ wv2, const float* __restrict__ bv,
    const float* __restrict__ bvc,
    unsigned short* __restrict__ qb, unsigned short* __restrict__ kbf,
    unsigned short* __restrict__ vt)
{
  __shared__ __align__(16) unsigned short smem[24576];  // 49152 B

  const int t  = threadIdx.x;
  const int nt = blockIdx.x;
  const int m0 = blockIdx.y << 7;

  const unsigned short* w2;
  const float *bias, *bisc;
  unsigned short* outp;
  float scl;
  int n0, N, mode;
  size_t mstride;
  if (nt < 2) {
    w2 = wq2; bias = bq; bisc = bqc; outp = qb; scl = QSCALE;
    n0 = nt << 7; N = 256; mode = 0; mstride = (size_t)256 * 1024;
  } else if (nt < 4) {
    w2 = wk2; bias = bk; bisc = bkc; outp = kbf; scl = 1.0f;
    n0 = (nt - 2) << 7; N = 256; mode = 0; mstride = (size_t)256 * 1024;
  } else {
    w2 = wv2; bias = bv; bisc = bvc; outp = vt; scl = 1.0f;
    n0 = (nt - 4) << 7; N = 1024; mode = 1; mstride = (size_t)1024 * 1024;
  }

  // --- per-thread source pointers for the 6 staging granule sets (kt = 0)
  // granule g = p*256 + t ; p 0-1 -> A, 2-3 -> B0, 4-5 -> B1
  const unsigned short* sA0;
  const unsigned short* sA1;
  {
    auto arow = [&](int g) -> const unsigned short* {
      const int row = g >> 2, ko = (g & 3) << 3;
      const int grow = m0 + row;
      const int bb0 = grow / SP_;
      const int ss0 = grow - bb0 * SP_;
      const int r = (grow < MTOT && ss0 < S_) ? (bb0 * S_ + ss0) : 0;
      return xh + (size_t)r * D_ + ko;
    };
    sA0 = arow(t);
    sA1 = arow(256 + t);
  }
  const int brow0 = t >> 2, bko0 = (t & 3) << 3;          // g in [0,256)
  const int brow1 = (256 + t) >> 2, bko1 = bko0;          // g in [256,512)
  const unsigned short* sB0 = w2 + (size_t)(n0 + brow0) * 1024 + bko0;
  const unsigned short* sB1 = w2 + (size_t)(n0 + brow1) * 1024 + bko1;
  const unsigned short* sG0 = sB0 + mstride;
  const unsigned short* sG1 = sB1 + mstride;

  const int lane = t & 63;
  const int w    = t >> 6;
  const int lo   = lane & 15;
  const int hi   = lane >> 4;
  const int wm   = (w & 1) << 6;
  const int wn   = (w >> 1) << 6;

  floatx4 lin[4][4], gat[4][4];
#pragma unroll
  for (int i = 0; i < 4; ++i)
#pragma unroll
    for (int j = 0; j < 4; ++j) {
      lin[i][j] = (floatx4){0.f, 0.f, 0.f, 0.f};
      gat[i][j] = (floatx4){0.f, 0.f, 0.f, 0.f};
    }

  auto stage = [&](int kt, int sel) {
    const int k0 = kt << 5;
    unsigned short* dst = &smem[sel * 12288 + t * 8];   // 16 B per lane
    gl_lds16(sA0 + k0, dst);
    gl_lds16(sA1 + k0, dst + 2048);
    gl_lds16(sB0 + k0, dst + 4096);
    gl_lds16(sB1 + k0, dst + 6144);
    gl_lds16(sG0 + k0, dst + 8192);
    gl_lds16(sG1 + k0, dst + 10240);
  };

  // --- pipeline: stage(t+1) in flight while computing tile t
  stage(0, 0);
  __syncthreads();   // drains vmcnt(0): buf0 ready

  for (int kt = 0; kt < 32; ++kt) {
    const int sel = kt & 1;
    if (kt < 31) stage(kt + 1, sel ^ 1);

    const unsigned short* Ab = &smem[sel * 12288];
    short8 ah[4];
#pragma unroll
    for (int i = 0; i < 4; ++i)
      ah[i] = *(const short8*)(Ab + (wm + i * 16 + lo) * 32 + hi * 8);
#pragma unroll
    for (int j = 0; j < 4; ++j) {
      const int cb = (wn + j * 16 + lo) * 32 + hi * 8;
      short8 bh = *(const short8*)(Ab + 4096 + cb);
      short8 gh = *(const short8*)(Ab + 8192 + cb);
#pragma unroll
      for (int i = 0; i < 4; ++i) {
        lin[i][j] = __builtin_amdgcn_mfma_f32_16x16x32_bf16(ah[i], bh, lin[i][j], 0, 0, 0);
        gat[i][j] = __builtin_amdgcn_mfma_f32_16x16x32_bf16(ah[i], gh, gat[i][j], 0, 0, 0);
      }
    }
    __syncthreads();  // reads of buf[sel] done AND stage(kt+1) drained
  }

  // ---- epilogue: stage bf16 tile in LDS, then coalesced 16 B stores
  unsigned short (*Os)[136] = reinterpret_cast<unsigned short (*)[136]>(&smem[0]);

#pragma unroll
  for (int j = 0; j < 4; ++j) {
    const int nl = wn + j * 16 + lo;
    const int n  = n0 + nl;
    const float bj = bias[n];
    const float cj = bisc[n];
#pragma unroll
    for (int i = 0; i < 4; ++i) {
      const int ml = wm + i * 16 + (hi << 2);
      unsigned short o16[4];
#pragma unroll
      for (int r = 0; r < 4; ++r) {
        const int gmr = m0 + ml + r;
        const int ssr = gmr - (gmr / SP_) * SP_;
        const bool padr = (ssr >= S_);          // x = 0 row -> bias-only
        float lv = (padr ? 0.f : lin[i][j][r]) + bj;
        float gv = (padr ? 0.f : gat[i][j][r]) + cj;
        o16[r] = f2b(scl * lv / (1.f + __expf(-gv)));
      }
      if (mode == 0) {
#pragma unroll
        for (int r = 0; r < 4; ++r) Os[ml + r][nl] = o16[r];
      } else {
        *(ushort4*)&Os[nl][ml] = make_ushort4(o16[0], o16[1], o16[2], o16[3]);
      }
    }
  }
  __syncthreads();

  // coalesced store: 16 consecutive lanes cover one 256 B row-run
#pragma unroll
  for (int c = 0; c < 8; ++c) {
    const int rr = (t >> 4) + 16 * c;   // Os row
    const int cc = (t & 15) << 3;       // Os col chunk (8 shorts = 16 B)
    uint4 val = *(const uint4*)&Os[rr][cc];
    if (mode == 0) {
      const int gm = m0 + rr;
      if (gm < MTOT)
        *(uint4*)(outp + (size_t)gm * N + n0 + cc) = val;
    } else {
      const int g = m0 + cc;            // 8-aligned; SP_ % 8 == 0 so no straddle
      if (g < MTOT) {
        const int vb = g / SP_;
        const int vs = g - vb * SP_;
        *(uint4*)(outp + (size_t)(vb * 1024 + n0 + rr) * SP_ + vs) = val;
      }
    }
  }
}

// ---------------------------------------------------------------------------
// MFMA flash attention v2: swapped 32x32x16 QK^T + fully in-register softmax.
// (unchanged from previous verified version)
// ---------------------------------------------------------------------------
__global__ __launch_bounds__(256, 4) void attn_mfma(
    const unsigned short* __restrict__ Q,   // bf16 [MTOT][256], pre-scaled
    const unsigned short* __restrict__ K,   // bf16 [MTOT][256]
    const unsigned short* __restrict__ VT,  // bf16 [B*1024][SP_]
    float* __restrict__ out)                // fp32 [B][S_][1024]
{
  const int bx = blockIdx.x;
  const int qt = bx & 15;
  const int h  = (bx >> 4) & 15;
  const int b  = bx >> 8;

  const int tid  = threadIdx.x;
  const int lane = tid & 63;
  const int w    = tid >> 6;
  const int l31  = lane & 31;
  const int h32  = lane >> 5;

  const int kbase = b * SP_;        // row base into Q/K
  const int hoff  = h << 4;         // head col offset (shorts)
  const int vbase = (b << 10) + (h << 6);  // row base into VT
  const int q0    = (qt << 7) + (w << 5);  // this wave's first query

  __shared__ __align__(16) unsigned short ksb[2][64 * 16];  // [key][kdim]
  __shared__ __align__(16) unsigned short vsb[2][512 * 8];  // [d][granule^],
                                                            // granule = 8 keys

  // Q B-frag: B[kd = 8*h32 + j][q = l31]  (16 B contiguous per lane)
  const short8 aq =
      *(const short8*)(Q + ((size_t)(kbase + q0 + l31) << 8) + hoff + (h32 << 3));

  floatx16 z16;
#pragma unroll
  for (int r = 0; r < 16; ++r) z16[r] = 0.f;
  floatx16 Of0 = z16, Of1 = z16;
  float lsum = 0.f;

  auto stage = [&](int kt, int sel) {
    const int j0 = kt << 6;
    // K tile: 64 keys x 16 kdims, linear dest = tid*16 B (tid<128)
    if (tid < 128) {
      int kr = j0 + (tid >> 1);
      if (kr >= SP_) kr = 0;  // clamp; masked via p=0 in tail chunk
      gl_lds16(K + ((size_t)(kbase + kr) << 8) + hoff + ((tid & 1) << 3),
               &ksb[sel][tid << 3]);
    }
    // V tile: 64 d-rows x 64 keys; dest linear, source inverse-swizzled so
    // stored granule g' holds keys (g'^(d&7))*8.. -> conflict-even b128 reads
#pragma unroll
    for (int pp = 0; pp < 2; ++pp) {
      const int gi = (pp << 8) + tid;
      const int d  = gi >> 3;
      int koff = j0 + (((gi & 7) ^ (d & 7)) << 3);
      if (koff > SP_ - 8) koff = SP_ - 8;  // tail clamp (data masked by p=0)
      gl_lds16(VT + (size_t)(vbase + d) * SP_ + koff, &vsb[sel][gi << 3]);
    }
  };

  auto chunk = [&](int c, bool tail8, int sel) {
    // A-frag: K[key = c*32 + l31][kd = 8*h32 + j]
    const short8 ak =
        *(const short8*)&ksb[sel][(((c << 5) + l31) << 4) + (h32 << 3)];
    // sc[r] = S^T[key = crow(r,h32)][q = l31]
    floatx16 sc = __builtin_amdgcn_mfma_f32_32x32x16_bf16(ak, aq, z16, 0, 0, 0);

    float p[16];
#pragma unroll
    for (int r = 0; r < 16; ++r) {
      float e = __builtin_amdgcn_exp2f(sc[r]);
      p[r] = (tail8 && r >= 8) ? 0.f : e;   // tail: crow>=16 invalid
    }
    lsum += (((p[0] + p[1]) + (p[2] + p[3])) + ((p[4] + p[5]) + (p[6] + p[7]))) +
            (((p[8] + p[9]) + (p[10] + p[11])) + ((p[12] + p[13]) + (p[14] + p[15])));

    // pack bf16 pairs; word m holds keys (crow(2m,h), crow(2m+1,h))
    const unsigned w0 = pk2(p[0], p[1]),   w1 = pk2(p[2], p[3]);
    const unsigned w2 = pk2(p[4], p[5]),   w3 = pk2(p[6], p[7]);
    const unsigned w4 = pk2(p[8], p[9]),   w5 = pk2(p[10], p[11]);
    const unsigned w6 = pk2(p[12], p[13]), w7 = pk2(p[14], p[15]);

    // permlane32_swap: out0 = {in0.lo | in1.lo->hi}, out1 = {in0.hi->lo | in1.hi}
    const uint2v a02 = __builtin_amdgcn_permlane32_swap(w0, w2, false, false);
    const uint2v a13 = __builtin_amdgcn_permlane32_swap(w1, w3, false, false);
    const uint2v a46 = __builtin_amdgcn_permlane32_swap(w4, w6, false, false);
    const uint2v a57 = __builtin_amdgcn_permlane32_swap(w5, w7, false, false);

    // PA frags: A[q = l31][key = kc*16 + 8*h32 + j]
    const short8 pa0 = __builtin_bit_cast(short8, (uintx4){a02[0], a13[0], a02[1], a13[1]});
    const short8 pa1 = __builtin_bit_cast(short8, (uintx4){a46[0], a57[0], a46[1], a57[1]});

#pragma unroll
    for (int dt = 0; dt < 2; ++dt) {
      const int dl = (dt << 5) + l31;
      const int rb = dl << 6;
      const int sw = dl & 7;
      // B-frag: V[key = c*32 + kc*16 + 8*h32 + j][d = dl], granule ^ (d&7)
      const short8 bv0 =
          *(const short8*)&vsb[sel][rb + ((((c << 2) + 0 + h32) ^ sw) << 3)];
      const short8 bv1 =
          *(const short8*)&vsb[sel][rb + ((((c << 2) + 2 + h32) ^ sw) << 3)];
      floatx16& O = dt ? Of1 : Of0;
      O = __builtin_amdgcn_mfma_f32_32x32x16_bf16(pa0, bv0, O, 0, 0, 0);
      O = __builtin_amdgcn_mfma_f32_32x32x16_bf16(pa1, bv1, O, 0, 0, 0);
    }
  };

  // 2-phase pipeline: stage(t+1) in flight while computing tile t;
  // __syncthreads() drains vmcnt+lgkmcnt once per 64-key tile.
  stage(0, 0);
  __syncthreads();
  for (int kt = 0; kt < 32; ++kt) {
    const int sel = kt & 1;
    stage(kt + 1, sel ^ 1);
    chunk(0, false, sel);
    chunk(1, false, sel);
    __syncthreads();
  }
  chunk(0, true, 0);  // tail tile (keys 2048..2063 valid)

  // epilogue: out[b][q][h*64 + d] = Of / l
  lsum += __shfl_xor(lsum, 32);   // combine the two key-half partial sums
  const float inv = 1.f / lsum;   // per q = l31, replicated across halves
#pragma unroll
  for (int r = 0; r < 16; ++r) {
    const int cr = (r & 3) + ((r >> 2) << 3) + (h32 << 2);  // crow(r,h32)
    const float invr = __shfl(inv, cr);   // transpose 1/l into C-layout
    const int qg = q0 + cr;
    float* op = out + (((size_t)(b * S_ + qg)) << 10) + (h << 6) + l31;
    op[0]  = Of0[r] * invr;
    op[32] = Of1[r] * invr;
  }
}

// ---------------------------------------------------------------------------
extern "C" void kernel_launch(void* const* d_in, const int* in_sizes, int n_in,
                              void* d_out, int out_size, void* d_ws, size_t ws_size,
                              hipStream_t stream) {
  (void)in_sizes; (void)n_in; (void)out_size; (void)ws_size;

  const float* x   = (const float*)d_in[0];
  const float* Wq  = (const float*)d_in[1];
  const float* bq  = (const float*)d_in[2];
  const float* Wqc = (const float*)d_in[3];
  const float* bqc = (const float*)d_in[4];
  const float* Wk  = (const float*)d_in[5];
  const float* bk  = (const float*)d_in[6];
  const float* Wkc = (const float*)d_in[7];
  const float* bkc = (const float*)d_in[8];
  const float* Wv  = (const float*)d_in[9];
  const float* bv  = (const float*)d_in[10];
  const float* Wvc = (const float*)d_in[11];
  const float* bvc = (const float*)d_in[12];
  float* out = (float*)d_out;

  // workspace layout (ushort units), total ~48 MB
  unsigned short* qb  = (unsigned short*)d_ws;
  unsigned short* kbf = qb  + (size_t)MTOT * 256;
  unsigned short* vt  = kbf + (size_t)MTOT * 256;
  unsigned short* xh  = vt  + (size_t)B_ * 1024 * SP_;
  unsigned short* wq2 = xh  + (size_t)B_ * S_ * D_;          // [2][256][1024]
  unsigned short* wk2 = wq2 + (size_t)2 * 256 * 1024;
  unsigned short* wv2 = wk2 + (size_t)2 * 256 * 1024;        // [2][1024][1024]

  dim3 blk(256);
  cast_x<<<(B_ * S_ * D_) / 1024, blk, 0, stream>>>(x, xh);

  wcast_t<<<dim3(8, 32),  blk, 0, stream>>>(Wq,   256, wq2);
  wcast_t<<<dim3(8, 32),  blk, 0, stream>>>(Wqc,  256, wq2 + 256 * 1024);
  wcast_t<<<dim3(8, 32),  blk, 0, stream>>>(Wk,   256, wk2);
  wcast_t<<<dim3(8, 32),  blk, 0, stream>>>(Wkc,  256, wk2 + 256 * 1024);
  wcast_t<<<dim3(32, 32), blk, 0, stream>>>(Wv,  1024, wv2);
  wcast_t<<<dim3(32, 32), blk, 0, stream>>>(Wvc, 1024, wv2 + 1024 * 1024);

  // merged q+k+v CSS GEMM: grid.x 0-1 -> q (pre-scaled by QSCALE), 2-3 -> k,
  // 4-11 -> v (transposed VT output)
  css_mfma2<<<dim3(12, 65), blk, 0, stream>>>(xh, wq2, bq, bqc, wk2, bk, bkc,
                                              wv2, bv, bvc, qb, kbf, vt);

  attn_mfma<<<B_ * H_ * (S_ / 128), blk, 0, stream>>>(qb, kbf, vt, out);
}

// Round 4
// 251.409 us; speedup vs baseline: 1.3813x; 1.0284x over previous
//
#include <hip/hip_runtime.h>
#include <hip/hip_bf16.h>
#include <cstdint>

// Problem constants
#define B_   4
#define S_   2048
#define SP_  2064        // S + 16 pad rows (pad rows: x == 0 -> bias-only qkv)
#define D_   1024
#define H_   16
#define MTOT (B_ * SP_)  // 8256 rows

// q is pre-scaled by 0.125 * log2(e) so softmax = exp2(q'.k) directly
#define QSCALE 0.18033688011112042f

typedef __attribute__((ext_vector_type(8))) short short8;
typedef __attribute__((ext_vector_type(4))) float floatx4;
typedef __attribute__((ext_vector_type(16))) float floatx16;
typedef __attribute__((ext_vector_type(2))) unsigned int uint2v;
typedef __attribute__((ext_vector_type(4))) unsigned int uintx4;

// fp32 -> bf16 round-to-nearest-even
static __device__ inline unsigned short f2b(float f) {
  unsigned u = __builtin_bit_cast(unsigned, f);
  u += 0x7FFFu + ((u >> 16) & 1u);
  return (unsigned short)(u >> 16);
}

// pack two fp32 -> bf16x2 word (round-half-away). Plain C (known VALU ops):
// an inline-asm def feeding permlane32_swap tripped a cross-lane hazard the
// compiler didn't model (R3 NaN) -- do NOT swap this back to v_cvt_pk asm.
static __device__ inline unsigned pk2(float a, float b) {
  unsigned ua = __builtin_bit_cast(unsigned, a) + 0x8000u;
  unsigned ub = __builtin_bit_cast(unsigned, b) + 0x8000u;
  return (ua >> 16) | (ub & 0xFFFF0000u);
}

// async global->LDS, 16 B per lane, dest = wave-uniform base + lane*16
static __device__ inline void gl_lds16(const unsigned short* g, unsigned short* l) {
  __builtin_amdgcn_global_load_lds((__attribute__((address_space(1))) void*)(g),
                                   (__attribute__((address_space(3))) void*)(l),
                                   16, 0, 0);
}

// ---------------------------------------------------------------------------
// Pre-pass 1: cast x (fp32) -> bf16.
// ---------------------------------------------------------------------------
__global__ __launch_bounds__(256) void cast_x(
    const float* __restrict__ x, unsigned short* __restrict__ xh)
{
  const int idx = (blockIdx.x * 256 + threadIdx.x) * 4;  // grid sized exactly
  float4 v = *(const float4*)(x + idx);
  ushort4 h;
  h.x = f2b(v.x); h.y = f2b(v.y); h.z = f2b(v.z); h.w = f2b(v.w);
  *(ushort4*)(xh + idx) = h;
}

// ---------------------------------------------------------------------------
// Pre-pass 2 (merged): transpose all six weights [1024][N] fp32 -> bf16 T.
// grid (96, 32): bx 0-7 Wq | 8-15 Wqc | 16-23 Wk | 24-31 Wkc | 32-63 Wv |
// 64-95 Wvc.
// ---------------------------------------------------------------------------
__global__ __launch_bounds__(256) void wcast_all(
    const float* __restrict__ Wq,  const float* __restrict__ Wqc,
    const float* __restrict__ Wk,  const float* __restrict__ Wkc,
    const float* __restrict__ Wv,  const float* __restrict__ Wvc,
    unsigned short* __restrict__ wq2, unsigned short* __restrict__ wk2,
    unsigned short* __restrict__ wv2)
{
  const int bx = blockIdx.x;
  const float* W; unsigned short* T; int N, nx;
  if (bx < 8)       { W = Wq;  T = wq2;               nx = bx;      N = 256;  }
  else if (bx < 16) { W = Wqc; T = wq2 + 256 * 1024;  nx = bx - 8;  N = 256;  }
  else if (bx < 24) { W = Wk;  T = wk2;               nx = bx - 16; N = 256;  }
  else if (bx < 32) { W = Wkc; T = wk2 + 256 * 1024;  nx = bx - 24; N = 256;  }
  else if (bx < 64) { W = Wv;  T = wv2;               nx = bx - 32; N = 1024; }
  else              { W = Wvc; T = wv2 + 1024 * 1024; nx = bx - 64; N = 1024; }

  __shared__ float tl[32][33];
  const int t  = threadIdx.x;
  const int n0 = nx * 32;
  const int k0 = blockIdx.y * 32;
  const int r  = t >> 3;
  const int c  = (t & 7) * 4;

  float4 w = *(const float4*)(W + (size_t)(k0 + r) * N + n0 + c);
  tl[r][c + 0] = w.x; tl[r][c + 1] = w.y; tl[r][c + 2] = w.z; tl[r][c + 3] = w.w;
  __syncthreads();

  ushort4 h;
  h.x = f2b(tl[c + 0][r]); h.y = f2b(tl[c + 1][r]);
  h.z = f2b(tl[c + 2][r]); h.w = f2b(tl[c + 3][r]);
  *(ushort4*)(T + (size_t)(n0 + r) * 1024 + k0 + c) = h;
}

// ---------------------------------------------------------------------------
// Merged CSS GEMM (q + k + v in ONE dispatch), m97-class structure.
//  * global_load_lds width=16 staging, double-buffered, ONE barrier/K-step.
//  * T2/rule-21 LDS swizzle: tile rows are 64 B (4 granules of 16 B);
//    stored slot s at (row) holds logical granule g = s ^ ((row>>1)&3)
//    (involution). Source address pre-swizzled; fragment reads XOR the
//    same term -> every 16-lane quarter of a ds_read_b128 hits all 8 bank
//    groups (2 lanes/group = free, m136) instead of 2 groups (8-way).
//  * grid (12, 65): nt 0-1 -> q, 2-3 -> k, 4-11 -> v (transposed VT out).
//  * pad rows (grow % SP_ >= S_) stage dummy data (row 0) and get the exact
//    bias-only value scl*b*sigmoid(c) in the epilogue.
// LDS: 2 x 3 x [128][32] = 48 KiB; epilogue Os[128][136] overlays it.
// ---------------------------------------------------------------------------
__global__ __launch_bounds__(256, 2) void css_mfma2(
    const unsigned short* __restrict__ xh,
    const unsigned short* __restrict__ wq2, const float* __restrict__ bq,
    const float* __restrict__ bqc,
    const unsigned short* __restrict__ wk2, const float* __restrict__ bk,
    const float* __restrict__ bkc,
    const unsigned short* __restrict__ wv2, const float* __restrict__ bv,
    const float* __restrict__ bvc,
    unsigned short* __restrict__ qb, unsigned short* __restrict__ kbf,
    unsigned short* __restrict__ vt)
{
  __shared__ __align__(16) unsigned short smem[24576];  // 49152 B

  const int t  = threadIdx.x;
  const int nt = blockIdx.x;
  const int m0 = blockIdx.y << 7;

  const unsigned short* w2;
  const float *bias, *bisc;
  unsigned short* outp;
  float scl;
  int n0, N, mode;
  size_t mstride;
  if (nt < 2) {
    w2 = wq2; bias = bq; bisc = bqc; outp = qb; scl = QSCALE;
    n0 = nt << 7; N = 256; mode = 0; mstride = (size_t)256 * 1024;
  } else if (nt < 4) {
    w2 = wk2; bias = bk; bisc = bkc; outp = kbf; scl = 1.0f;
    n0 = (nt - 2) << 7; N = 256; mode = 0; mstride = (size_t)256 * 1024;
  } else {
    w2 = wv2; bias = bv; bisc = bvc; outp = vt; scl = 1.0f;
    n0 = (nt - 4) << 7; N = 1024; mode = 1; mstride = (size_t)1024 * 1024;
  }

  // --- staging source pointers. Thread t stages granules t and 256+t of
  // each tile; LDS dest is linear (t*16 B), so the SOURCE column carries the
  // swizzle: logical granule g = (t&3) ^ ((row>>1)&3), row = t>>2 (both
  // granule sets of a tile differ by 64 rows -> same swizzle term).
  const int ko_s = (((t & 3) ^ ((t >> 3) & 3)) << 3);  // swizzled col (shorts)

  const unsigned short* sA0;
  const unsigned short* sA1;
  {
    auto arow = [&](int row) -> const unsigned short* {
      const int grow = m0 + row;
      const int bb0 = grow / SP_;
      const int ss0 = grow - bb0 * SP_;
      const int r = (grow < MTOT && ss0 < S_) ? (bb0 * S_ + ss0) : 0;
      return xh + (size_t)r * D_ + ko_s;
    };
    sA0 = arow(t >> 2);
    sA1 = arow(64 + (t >> 2));
  }
  const int brow0 = t >> 2;
  const int brow1 = 64 + (t >> 2);
  const unsigned short* sB0 = w2 + (size_t)(n0 + brow0) * 1024 + ko_s;
  const unsigned short* sB1 = w2 + (size_t)(n0 + brow1) * 1024 + ko_s;
  const unsigned short* sG0 = sB0 + mstride;
  const unsigned short* sG1 = sB1 + mstride;

  const int lane = t & 63;
  const int w    = t >> 6;
  const int lo   = lane & 15;
  const int hi   = lane >> 4;
  const int wm   = (w & 1) << 6;
  const int wn   = (w >> 1) << 6;

  // fragment-read swizzle slot: rows are wm/wn + i*16 + lo (base mult. of 16)
  // -> ((row>>1)&3) == ((lo>>1)&3), loop-invariant.
  const int sl8 = ((hi ^ ((lo >> 1) & 3)) << 3);

  floatx4 lin[4][4], gat[4][4];
#pragma unroll
  for (int i = 0; i < 4; ++i)
#pragma unroll
    for (int j = 0; j < 4; ++j) {
      lin[i][j] = (floatx4){0.f, 0.f, 0.f, 0.f};
      gat[i][j] = (floatx4){0.f, 0.f, 0.f, 0.f};
    }

  auto stage = [&](int kt, int sel) {
    const int k0 = kt << 5;
    unsigned short* dst = &smem[sel * 12288 + t * 8];   // 16 B per lane
    gl_lds16(sA0 + k0, dst);
    gl_lds16(sA1 + k0, dst + 2048);
    gl_lds16(sB0 + k0, dst + 4096);
    gl_lds16(sB1 + k0, dst + 6144);
    gl_lds16(sG0 + k0, dst + 8192);
    gl_lds16(sG1 + k0, dst + 10240);
  };

  // --- pipeline: stage(t+1) in flight while computing tile t
  stage(0, 0);
  __syncthreads();   // drains vmcnt(0): buf0 ready

  for (int kt = 0; kt < 32; ++kt) {
    const int sel = kt & 1;
    if (kt < 31) stage(kt + 1, sel ^ 1);

    const unsigned short* Ab = &smem[sel * 12288];
    short8 ah[4];
#pragma unroll
    for (int i = 0; i < 4; ++i)
      ah[i] = *(const short8*)(Ab + (wm + i * 16 + lo) * 32 + sl8);
#pragma unroll
    for (int j = 0; j < 4; ++j) {
      const int cb = (wn + j * 16 + lo) * 32 + sl8;
      short8 bh = *(const short8*)(Ab + 4096 + cb);
      short8 gh = *(const short8*)(Ab + 8192 + cb);
#pragma unroll
      for (int i = 0; i < 4; ++i) {
        lin[i][j] = __builtin_amdgcn_mfma_f32_16x16x32_bf16(ah[i], bh, lin[i][j], 0, 0, 0);
        gat[i][j] = __builtin_amdgcn_mfma_f32_16x16x32_bf16(ah[i], gh, gat[i][j], 0, 0, 0);
      }
    }
    __syncthreads();  // reads of buf[sel] done AND stage(kt+1) drained
  }

  // ---- epilogue: stage bf16 tile in LDS, then coalesced 16 B stores
  unsigned short (*Os)[136] = reinterpret_cast<unsigned short (*)[136]>(&smem[0]);

#pragma unroll
  for (int j = 0; j < 4; ++j) {
    const int nl = wn + j * 16 + lo;
    const int n  = n0 + nl;
    const float bj = bias[n];
    const float cj = bisc[n];
#pragma unroll
    for (int i = 0; i < 4; ++i) {
      const int ml = wm + i * 16 + (hi << 2);
      unsigned short o16[4];
#pragma unroll
      for (int r = 0; r < 4; ++r) {
        const int gmr = m0 + ml + r;
        const int ssr = gmr - (gmr / SP_) * SP_;
        const bool padr = (ssr >= S_);          // x = 0 row -> bias-only
        float lv = (padr ? 0.f : lin[i][j][r]) + bj;
        float gv = (padr ? 0.f : gat[i][j][r]) + cj;
        o16[r] = f2b(scl * lv / (1.f + __expf(-gv)));
      }
      if (mode == 0) {
#pragma unroll
        for (int r = 0; r < 4; ++r) Os[ml + r][nl] = o16[r];
      } else {
        *(ushort4*)&Os[nl][ml] = make_ushort4(o16[0], o16[1], o16[2], o16[3]);
      }
    }
  }
  __syncthreads();

  // coalesced store: 16 consecutive lanes cover one 256 B row-run
#pragma unroll
  for (int c = 0; c < 8; ++c) {
    const int rr = (t >> 4) + 16 * c;   // Os row
    const int cc = (t & 15) << 3;       // Os col chunk (8 shorts = 16 B)
    uint4 val = *(const uint4*)&Os[rr][cc];
    if (mode == 0) {
      const int gm = m0 + rr;
      if (gm < MTOT)
        *(uint4*)(outp + (size_t)gm * N + n0 + cc) = val;
    } else {
      const int g = m0 + cc;            // 8-aligned; SP_ % 8 == 0 so no straddle
      if (g < MTOT) {
        const int vb = g / SP_;
        const int vs = g - vb * SP_;
        *(uint4*)(outp + (size_t)(vb * 1024 + n0 + rr) * SP_ + vs) = val;
      }
    }
  }
}

// ---------------------------------------------------------------------------
// MFMA flash attention v3: swapped 32x32x16 QK^T, in-register softmax,
// row-sum via ones-MFMA (lands directly in C-layout -> no adds, no shuffles),
// pk2 plain-C bf16 packing (inline-asm cvt_pk -> permlane tripped an
// unmodeled cross-lane hazard; keep the pack in compiler-known VALU ops).
// ---------------------------------------------------------------------------
__global__ __launch_bounds__(256, 4) void attn_mfma(
    const unsigned short* __restrict__ Q,   // bf16 [MTOT][256], pre-scaled
    const unsigned short* __restrict__ K,   // bf16 [MTOT][256]
    const unsigned short* __restrict__ VT,  // bf16 [B*1024][SP_]
    float* __restrict__ out)                // fp32 [B][S_][1024]
{
  const int bx = blockIdx.x;
  const int qt = bx & 15;
  const int h  = (bx >> 4) & 15;
  const int b  = bx >> 8;

  const int tid  = threadIdx.x;
  const int lane = tid & 63;
  const int w    = tid >> 6;
  const int l31  = lane & 31;
  const int h32  = lane >> 5;

  const int kbase = b * SP_;        // row base into Q/K
  const int hoff  = h << 4;         // head col offset (shorts)
  const int vbase = (b << 10) + (h << 6);  // row base into VT
  const int q0    = (qt << 7) + (w << 5);  // this wave's first query

  __shared__ __align__(16) unsigned short ksb[2][64 * 16];  // [key][kdim]
  __shared__ __align__(16) unsigned short vsb[2][512 * 8];  // [d][granule^]

  // Q B-frag: B[kd = 8*h32 + j][q = l31]  (16 B contiguous per lane)
  const short8 aq =
      *(const short8*)(Q + ((size_t)(kbase + q0 + l31) << 8) + hoff + (h32 << 3));

  floatx16 z16;
#pragma unroll
  for (int r = 0; r < 16; ++r) z16[r] = 0.f;
  floatx16 Of0 = z16, Of1 = z16, Ol = z16;

  const short one_bf = (short)0x3F80;                 // bf16 1.0
  const short8 ones = {one_bf, one_bf, one_bf, one_bf,
                       one_bf, one_bf, one_bf, one_bf};

  // pre-hoisted LDS offsets (shorts); dt=1 adds 2048 ((32+l31)&7 == l31&7)
  const int ak0 = (l31 << 4) + (h32 << 3);
  const int ak1 = ((32 + l31) << 4) + (h32 << 3);
  const int rb0 = l31 << 6;
  const int sw0 = l31 & 7;
  const int v00 = rb0 + (((0 + h32) ^ sw0) << 3);  // c=0, pair 0
  const int v01 = rb0 + (((2 + h32) ^ sw0) << 3);  // c=0, pair 1
  const int v10 = rb0 + (((4 + h32) ^ sw0) << 3);  // c=1, pair 0
  const int v11 = rb0 + (((6 + h32) ^ sw0) << 3);  // c=1, pair 1

  auto stage = [&](int kt, int sel) {
    const int j0 = kt << 6;
    // K tile: 64 keys x 16 kdims, linear dest = tid*16 B (tid<128)
    if (tid < 128) {
      int kr = j0 + (tid >> 1);
      if (kr >= SP_) kr = 0;  // clamp; masked via p=0 in tail chunk
      gl_lds16(K + ((size_t)(kbase + kr) << 8) + hoff + ((tid & 1) << 3),
               &ksb[sel][tid << 3]);
    }
    // V tile: 64 d-rows x 64 keys; dest linear, source inverse-swizzled so
    // stored granule g' holds keys (g'^(d&7))*8.. -> conflict-even b128 reads
#pragma unroll
    for (int pp = 0; pp < 2; ++pp) {
      const int gi = (pp << 8) + tid;
      const int d  = gi >> 3;
      int koff = j0 + (((gi & 7) ^ (d & 7)) << 3);
      if (koff > SP_ - 8) koff = SP_ - 8;  // tail clamp (data masked by p=0)
      gl_lds16(VT + (size_t)(vbase + d) * SP_ + koff, &vsb[sel][gi << 3]);
    }
  };

  auto chunk = [&](int c, bool tail8, int sel) {
    // A-frag: K[key = c*32 + l31][kd = 8*h32 + j]
    const short8 ak = *(const short8*)&ksb[sel][c ? ak1 : ak0];
    // sc[r] = S^T[key = crow(r,h32)][q = l31]
    floatx16 sc = __builtin_amdgcn_mfma_f32_32x32x16_bf16(ak, aq, z16, 0, 0, 0);

    float p[16];
#pragma unroll
    for (int r = 0; r < 16; ++r) {
      float e = __builtin_amdgcn_exp2f(sc[r]);
      p[r] = (tail8 && r >= 8) ? 0.f : e;   // tail: crow>=16 invalid
    }

    // pack bf16 pairs; word m holds keys crow(2m..2m+1,h)
    const unsigned w0 = pk2(p[0], p[1]),   w1 = pk2(p[2], p[3]);
    const unsigned w2 = pk2(p[4], p[5]),   w3 = pk2(p[6], p[7]);
    const unsigned w4 = pk2(p[8], p[9]),   w5 = pk2(p[10], p[11]);
    const unsigned w6 = pk2(p[12], p[13]), w7 = pk2(p[14], p[15]);

    // permlane32_swap: out0 = {in0.lo | in1.lo->hi}, out1 = {in0.hi->lo | in1.hi}
    const uint2v a02 = __builtin_amdgcn_permlane32_swap(w0, w2, false, false);
    const uint2v a13 = __builtin_amdgcn_permlane32_swap(w1, w3, false, false);
    const uint2v a46 = __builtin_amdgcn_permlane32_swap(w4, w6, false, false);
    const uint2v a57 = __builtin_amdgcn_permlane32_swap(w5, w7, false, false);

    // PA frags: A[q = l31][key = kc*16 + 8*h32 + j]
    const short8 pa0 = __builtin_bit_cast(short8, (uintx4){a02[0], a13[0], a02[1], a13[1]});
    const short8 pa1 = __builtin_bit_cast(short8, (uintx4){a46[0], a57[0], a46[1], a57[1]});

    // row-sum on the MFMA pipe: C[q][*] = sum_k P[q][k] -- same C-layout as
    // Of, so the epilogue divides element-wise with ZERO cross-lane traffic.
    Ol = __builtin_amdgcn_mfma_f32_32x32x16_bf16(pa0, ones, Ol, 0, 0, 0);
    Ol = __builtin_amdgcn_mfma_f32_32x32x16_bf16(pa1, ones, Ol, 0, 0, 0);

    const int o0 = c ? v10 : v00;
    const int o1 = c ? v11 : v01;
    {
      const short8 bv0 = *(const short8*)&vsb[sel][o0];
      const short8 bv1 = *(const short8*)&vsb[sel][o1];
      Of0 = __builtin_amdgcn_mfma_f32_32x32x16_bf16(pa0, bv0, Of0, 0, 0, 0);
      Of0 = __builtin_amdgcn_mfma_f32_32x32x16_bf16(pa1, bv1, Of0, 0, 0, 0);
    }
    {
      const short8 bv0 = *(const short8*)&vsb[sel][o0 + 2048];
      const short8 bv1 = *(const short8*)&vsb[sel][o1 + 2048];
      Of1 = __builtin_amdgcn_mfma_f32_32x32x16_bf16(pa0, bv0, Of1, 0, 0, 0);
      Of1 = __builtin_amdgcn_mfma_f32_32x32x16_bf16(pa1, bv1, Of1, 0, 0, 0);
    }
  };

  // 2-phase pipeline: stage(t+1) in flight while computing tile t;
  // __syncthreads() drains vmcnt+lgkmcnt once per 64-key tile.
  stage(0, 0);
  __syncthreads();
  for (int kt = 0; kt < 32; ++kt) {
    const int sel = kt & 1;
    stage(kt + 1, sel ^ 1);
    chunk(0, false, sel);
    chunk(1, false, sel);
    __syncthreads();
  }
  chunk(0, true, 0);  // tail tile (keys 2048..2063 valid)

  // epilogue: out[b][q][h*64 + d] = Of / Ol (all three share the C-layout)
#pragma unroll
  for (int r = 0; r < 16; ++r) {
    const int cr = (r & 3) + ((r >> 2) << 3) + (h32 << 2);  // crow(r,h32)
    const float invr = 1.f / Ol[r];
    const int qg = q0 + cr;
    float* op = out + (((size_t)(b * S_ + qg)) << 10) + (h << 6) + l31;
    op[0]  = Of0[r] * invr;
    op[32] = Of1[r] * invr;
  }
}

// ---------------------------------------------------------------------------
extern "C" void kernel_launch(void* const* d_in, const int* in_sizes, int n_in,
                              void* d_out, int out_size, void* d_ws, size_t ws_size,
                              hipStream_t stream) {
  (void)in_sizes; (void)n_in; (void)out_size; (void)ws_size;

  const float* x   = (const float*)d_in[0];
  const float* Wq  = (const float*)d_in[1];
  const float* bq  = (const float*)d_in[2];
  const float* Wqc = (const float*)d_in[3];
  const float* bqc = (const float*)d_in[4];
  const float* Wk  = (const float*)d_in[5];
  const float* bk  = (const float*)d_in[6];
  const float* Wkc = (const float*)d_in[7];
  const float* bkc = (const float*)d_in[8];
  const float* Wv  = (const float*)d_in[9];
  const float* bv  = (const float*)d_in[10];
  const float* Wvc = (const float*)d_in[11];
  const float* bvc = (const float*)d_in[12];
  float* out = (float*)d_out;

  // workspace layout (ushort units), total ~48 MB
  unsigned short* qb  = (unsigned short*)d_ws;
  unsigned short* kbf = qb  + (size_t)MTOT * 256;
  unsigned short* vt  = kbf + (size_t)MTOT * 256;
  unsigned short* xh  = vt  + (size_t)B_ * 1024 * SP_;
  unsigned short* wq2 = xh  + (size_t)B_ * S_ * D_;          // [2][256][1024]
  unsigned short* wk2 = wq2 + (size_t)2 * 256 * 1024;
  unsigned short* wv2 = wk2 + (size_t)2 * 256 * 1024;        // [2][1024][1024]

  dim3 blk(256);
  cast_x<<<(B_ * S_ * D_) / 1024, blk, 0, stream>>>(x, xh);

  wcast_all<<<dim3(96, 32), blk, 0, stream>>>(Wq, Wqc, Wk, Wkc, Wv, Wvc,
                                              wq2, wk2, wv2);

  // merged q+k+v CSS GEMM: grid.x 0-1 -> q (pre-scaled by QSCALE), 2-3 -> k,
  // 4-11 -> v (transposed VT output)
  css_mfma2<<<dim3(12, 65), blk, 0, stream>>>(xh, wq2, bq, bqc, wk2, bk, bkc,
                                              wv2, bv, bvc, qb, kbf, vt);

  attn_mfma<<<B_ * H_ * (S_ / 128), blk, 0, stream>>>(qb, kbf, vt, out);
}

// Round 5
// 251.079 us; speedup vs baseline: 1.3831x; 1.0013x over previous
//
#include <hip/hip_runtime.h>
#include <hip/hip_bf16.h>
#include <cstdint>

// Problem constants
#define B_   4
#define S_   2048
#define SP_  2064        // S + 16 pad rows (pad rows: x == 0 -> bias-only qkv)
#define D_   1024
#define H_   16
#define MTOT (B_ * SP_)  // 8256 rows

// q is pre-scaled by 0.125 * log2(e) so softmax = exp2(q'.k) directly
#define QSCALE 0.18033688011112042f

typedef __attribute__((ext_vector_type(8))) short short8;
typedef __attribute__((ext_vector_type(4))) float floatx4;
typedef __attribute__((ext_vector_type(16))) float floatx16;
typedef __attribute__((ext_vector_type(2))) unsigned int uint2v;
typedef __attribute__((ext_vector_type(4))) unsigned int uintx4;

// fp32 -> bf16 round-to-nearest-even
static __device__ inline unsigned short f2b(float f) {
  unsigned u = __builtin_bit_cast(unsigned, f);
  u += 0x7FFFu + ((u >> 16) & 1u);
  return (unsigned short)(u >> 16);
}

// pack two fp32 -> bf16x2 word (round-half-away). Plain C (known VALU ops):
// an inline-asm def feeding permlane32_swap tripped a cross-lane hazard the
// compiler didn't model (R3 NaN) -- do NOT swap this back to v_cvt_pk asm.
static __device__ inline unsigned pk2(float a, float b) {
  unsigned ua = __builtin_bit_cast(unsigned, a) + 0x8000u;
  unsigned ub = __builtin_bit_cast(unsigned, b) + 0x8000u;
  return (ua >> 16) | (ub & 0xFFFF0000u);
}

// async global->LDS, 16 B per lane, dest = wave-uniform base + lane*16
static __device__ inline void gl_lds16(const unsigned short* g, unsigned short* l) {
  __builtin_amdgcn_global_load_lds((__attribute__((address_space(1))) void*)(g),
                                   (__attribute__((address_space(3))) void*)(l),
                                   16, 0, 0);
}

// ---------------------------------------------------------------------------
// Pre-pass 1: cast x (fp32) -> bf16.
// ---------------------------------------------------------------------------
__global__ __launch_bounds__(256) void cast_x(
    const float* __restrict__ x, unsigned short* __restrict__ xh)
{
  const int idx = (blockIdx.x * 256 + threadIdx.x) * 4;  // grid sized exactly
  float4 v = *(const float4*)(x + idx);
  ushort4 h;
  h.x = f2b(v.x); h.y = f2b(v.y); h.z = f2b(v.z); h.w = f2b(v.w);
  *(ushort4*)(xh + idx) = h;
}

// ---------------------------------------------------------------------------
// Pre-pass 2 (merged): transpose all six weights [1024][N] fp32 -> bf16 T.
// grid (96, 32): bx 0-7 Wq | 8-15 Wqc | 16-23 Wk | 24-31 Wkc | 32-63 Wv |
// 64-95 Wvc.
// ---------------------------------------------------------------------------
__global__ __launch_bounds__(256) void wcast_all(
    const float* __restrict__ Wq,  const float* __restrict__ Wqc,
    const float* __restrict__ Wk,  const float* __restrict__ Wkc,
    const float* __restrict__ Wv,  const float* __restrict__ Wvc,
    unsigned short* __restrict__ wq2, unsigned short* __restrict__ wk2,
    unsigned short* __restrict__ wv2)
{
  const int bx = blockIdx.x;
  const float* W; unsigned short* T; int N, nx;
  if (bx < 8)       { W = Wq;  T = wq2;               nx = bx;      N = 256;  }
  else if (bx < 16) { W = Wqc; T = wq2 + 256 * 1024;  nx = bx - 8;  N = 256;  }
  else if (bx < 24) { W = Wk;  T = wk2;               nx = bx - 16; N = 256;  }
  else if (bx < 32) { W = Wkc; T = wk2 + 256 * 1024;  nx = bx - 24; N = 256;  }
  else if (bx < 64) { W = Wv;  T = wv2;               nx = bx - 32; N = 1024; }
  else              { W = Wvc; T = wv2 + 1024 * 1024; nx = bx - 64; N = 1024; }

  __shared__ float tl[32][33];
  const int t  = threadIdx.x;
  const int n0 = nx * 32;
  const int k0 = blockIdx.y * 32;
  const int r  = t >> 3;
  const int c  = (t & 7) * 4;

  float4 w = *(const float4*)(W + (size_t)(k0 + r) * N + n0 + c);
  tl[r][c + 0] = w.x; tl[r][c + 1] = w.y; tl[r][c + 2] = w.z; tl[r][c + 3] = w.w;
  __syncthreads();

  ushort4 h;
  h.x = f2b(tl[c + 0][r]); h.y = f2b(tl[c + 1][r]);
  h.z = f2b(tl[c + 2][r]); h.w = f2b(tl[c + 3][r]);
  *(ushort4*)(T + (size_t)(n0 + r) * 1024 + k0 + c) = h;
}

// ---------------------------------------------------------------------------
// Merged CSS GEMM (q + k + v in ONE dispatch), m97-class structure.
// (unchanged from R4 verified version)
// ---------------------------------------------------------------------------
__global__ __launch_bounds__(256, 2) void css_mfma2(
    const unsigned short* __restrict__ xh,
    const unsigned short* __restrict__ wq2, const float* __restrict__ bq,
    const float* __restrict__ bqc,
    const unsigned short* __restrict__ wk2, const float* __restrict__ bk,
    const float* __restrict__ bkc,
    const unsigned short* __restrict__ wv2, const float* __restrict__ bv,
    const float* __restrict__ bvc,
    unsigned short* __restrict__ qb, unsigned short* __restrict__ kbf,
    unsigned short* __restrict__ vt)
{
  __shared__ __align__(16) unsigned short smem[24576];  // 49152 B

  const int t  = threadIdx.x;
  const int nt = blockIdx.x;
  const int m0 = blockIdx.y << 7;

  const unsigned short* w2;
  const float *bias, *bisc;
  unsigned short* outp;
  float scl;
  int n0, N, mode;
  size_t mstride;
  if (nt < 2) {
    w2 = wq2; bias = bq; bisc = bqc; outp = qb; scl = QSCALE;
    n0 = nt << 7; N = 256; mode = 0; mstride = (size_t)256 * 1024;
  } else if (nt < 4) {
    w2 = wk2; bias = bk; bisc = bkc; outp = kbf; scl = 1.0f;
    n0 = (nt - 2) << 7; N = 256; mode = 0; mstride = (size_t)256 * 1024;
  } else {
    w2 = wv2; bias = bv; bisc = bvc; outp = vt; scl = 1.0f;
    n0 = (nt - 4) << 7; N = 1024; mode = 1; mstride = (size_t)1024 * 1024;
  }

  // --- staging source pointers. Thread t stages granules t and 256+t of
  // each tile; LDS dest is linear (t*16 B), so the SOURCE column carries the
  // swizzle: logical granule g = (t&3) ^ ((row>>1)&3), row = t>>2 (both
  // granule sets of a tile differ by 64 rows -> same swizzle term).
  const int ko_s = (((t & 3) ^ ((t >> 3) & 3)) << 3);  // swizzled col (shorts)

  const unsigned short* sA0;
  const unsigned short* sA1;
  {
    auto arow = [&](int row) -> const unsigned short* {
      const int grow = m0 + row;
      const int bb0 = grow / SP_;
      const int ss0 = grow - bb0 * SP_;
      const int r = (grow < MTOT && ss0 < S_) ? (bb0 * S_ + ss0) : 0;
      return xh + (size_t)r * D_ + ko_s;
    };
    sA0 = arow(t >> 2);
    sA1 = arow(64 + (t >> 2));
  }
  const int brow0 = t >> 2;
  const int brow1 = 64 + (t >> 2);
  const unsigned short* sB0 = w2 + (size_t)(n0 + brow0) * 1024 + ko_s;
  const unsigned short* sB1 = w2 + (size_t)(n0 + brow1) * 1024 + ko_s;
  const unsigned short* sG0 = sB0 + mstride;
  const unsigned short* sG1 = sB1 + mstride;

  const int lane = t & 63;
  const int w    = t >> 6;
  const int lo   = lane & 15;
  const int hi   = lane >> 4;
  const int wm   = (w & 1) << 6;
  const int wn   = (w >> 1) << 6;

  // fragment-read swizzle slot: rows are wm/wn + i*16 + lo (base mult. of 16)
  // -> ((row>>1)&3) == ((lo>>1)&3), loop-invariant.
  const int sl8 = ((hi ^ ((lo >> 1) & 3)) << 3);

  floatx4 lin[4][4], gat[4][4];
#pragma unroll
  for (int i = 0; i < 4; ++i)
#pragma unroll
    for (int j = 0; j < 4; ++j) {
      lin[i][j] = (floatx4){0.f, 0.f, 0.f, 0.f};
      gat[i][j] = (floatx4){0.f, 0.f, 0.f, 0.f};
    }

  auto stage = [&](int kt, int sel) {
    const int k0 = kt << 5;
    unsigned short* dst = &smem[sel * 12288 + t * 8];   // 16 B per lane
    gl_lds16(sA0 + k0, dst);
    gl_lds16(sA1 + k0, dst + 2048);
    gl_lds16(sB0 + k0, dst + 4096);
    gl_lds16(sB1 + k0, dst + 6144);
    gl_lds16(sG0 + k0, dst + 8192);
    gl_lds16(sG1 + k0, dst + 10240);
  };

  // --- pipeline: stage(t+1) in flight while computing tile t
  stage(0, 0);
  __syncthreads();   // drains vmcnt(0): buf0 ready

  for (int kt = 0; kt < 32; ++kt) {
    const int sel = kt & 1;
    if (kt < 31) stage(kt + 1, sel ^ 1);

    const unsigned short* Ab = &smem[sel * 12288];
    short8 ah[4];
#pragma unroll
    for (int i = 0; i < 4; ++i)
      ah[i] = *(const short8*)(Ab + (wm + i * 16 + lo) * 32 + sl8);
#pragma unroll
    for (int j = 0; j < 4; ++j) {
      const int cb = (wn + j * 16 + lo) * 32 + sl8;
      short8 bh = *(const short8*)(Ab + 4096 + cb);
      short8 gh = *(const short8*)(Ab + 8192 + cb);
#pragma unroll
      for (int i = 0; i < 4; ++i) {
        lin[i][j] = __builtin_amdgcn_mfma_f32_16x16x32_bf16(ah[i], bh, lin[i][j], 0, 0, 0);
        gat[i][j] = __builtin_amdgcn_mfma_f32_16x16x32_bf16(ah[i], gh, gat[i][j], 0, 0, 0);
      }
    }
    __syncthreads();  // reads of buf[sel] done AND stage(kt+1) drained
  }

  // ---- epilogue: stage bf16 tile in LDS, then coalesced 16 B stores
  unsigned short (*Os)[136] = reinterpret_cast<unsigned short (*)[136]>(&smem[0]);

#pragma unroll
  for (int j = 0; j < 4; ++j) {
    const int nl = wn + j * 16 + lo;
    const int n  = n0 + nl;
    const float bj = bias[n];
    const float cj = bisc[n];
#pragma unroll
    for (int i = 0; i < 4; ++i) {
      const int ml = wm + i * 16 + (hi << 2);
      unsigned short o16[4];
#pragma unroll
      for (int r = 0; r < 4; ++r) {
        const int gmr = m0 + ml + r;
        const int ssr = gmr - (gmr / SP_) * SP_;
        const bool padr = (ssr >= S_);          // x = 0 row -> bias-only
        float lv = (padr ? 0.f : lin[i][j][r]) + bj;
        float gv = (padr ? 0.f : gat[i][j][r]) + cj;
        o16[r] = f2b(scl * lv / (1.f + __expf(-gv)));
      }
      if (mode == 0) {
#pragma unroll
        for (int r = 0; r < 4; ++r) Os[ml + r][nl] = o16[r];
      } else {
        *(ushort4*)&Os[nl][ml] = make_ushort4(o16[0], o16[1], o16[2], o16[3]);
      }
    }
  }
  __syncthreads();

  // coalesced store: 16 consecutive lanes cover one 256 B row-run
#pragma unroll
  for (int c = 0; c < 8; ++c) {
    const int rr = (t >> 4) + 16 * c;   // Os row
    const int cc = (t & 15) << 3;       // Os col chunk (8 shorts = 16 B)
    uint4 val = *(const uint4*)&Os[rr][cc];
    if (mode == 0) {
      const int gm = m0 + rr;
      if (gm < MTOT)
        *(uint4*)(outp + (size_t)gm * N + n0 + cc) = val;
    } else {
      const int g = m0 + cc;            // 8-aligned; SP_ % 8 == 0 so no straddle
      if (g < MTOT) {
        const int vb = g / SP_;
        const int vs = g - vb * SP_;
        *(uint4*)(outp + (size_t)(vb * 1024 + n0 + rr) * SP_ + vs) = val;
      }
    }
  }
}

// ---------------------------------------------------------------------------
// MFMA flash attention v4:
//  * XCD-aware block swizzle (T1): 1024 blocks = 8 XCDs x 128; each XCD owns
//    8 contiguous (b,h) pairs -> their K/V working set (2.6 MB) is
//    L2-resident instead of being re-fetched by all 8 XCDs (FETCH 86 MB ->
//    ~compulsory).
//  * Triple-buffered K/V staging with COUNTED vmcnt (T3/T4): stage(kt+2)
//    issued while tile kt computes; the barrier waits vmcnt(3)/(2) (waves
//    0-1 issue 3 VMEM/stage, waves 2-3 issue 2 -- vmcnt is per-wave) so the
//    next prefetch stays in flight across the barrier. vmcnt(0) only once,
//    at the last staged tile. Raw s_barrier (no compiler-forced full drain).
//  * Rest as v3: swapped 32x32x16 QK^T, in-register softmax, ones-MFMA
//    row-sum in C-layout, pk2 plain-C packing.
// ---------------------------------------------------------------------------
__global__ __launch_bounds__(256, 4) void attn_mfma(
    const unsigned short* __restrict__ Q,   // bf16 [MTOT][256], pre-scaled
    const unsigned short* __restrict__ K,   // bf16 [MTOT][256]
    const unsigned short* __restrict__ VT,  // bf16 [B*1024][SP_]
    float* __restrict__ out)                // fp32 [B][S_][1024]
{
  // T1: HW round-robins consecutive blockIdx across XCDs; remap so each XCD
  // gets a contiguous 128-block chunk (= 8 (b,h) pairs). Bijective: 1024=8*128.
  const int bx = ((blockIdx.x & 7) << 7) + (blockIdx.x >> 3);
  const int qt = bx & 15;
  const int h  = (bx >> 4) & 15;
  const int b  = bx >> 8;

  const int tid  = threadIdx.x;
  const int lane = tid & 63;
  const int w    = tid >> 6;
  const int l31  = lane & 31;
  const int h32  = lane >> 5;

  const int kbase = b * SP_;        // row base into Q/K
  const int hoff  = h << 4;         // head col offset (shorts)
  const int vbase = (b << 10) + (h << 6);  // row base into VT
  const int q0    = (qt << 7) + (w << 5);  // this wave's first query

  __shared__ __align__(16) unsigned short ksb[3][64 * 16];  // [key][kdim]
  __shared__ __align__(16) unsigned short vsb[3][512 * 8];  // [d][granule^]

  // Q B-frag: B[kd = 8*h32 + j][q = l31]  (16 B contiguous per lane)
  const short8 aq =
      *(const short8*)(Q + ((size_t)(kbase + q0 + l31) << 8) + hoff + (h32 << 3));

  floatx16 z16;
#pragma unroll
  for (int r = 0; r < 16; ++r) z16[r] = 0.f;
  floatx16 Of0 = z16, Of1 = z16, Ol = z16;

  const short one_bf = (short)0x3F80;                 // bf16 1.0
  const short8 ones = {one_bf, one_bf, one_bf, one_bf,
                       one_bf, one_bf, one_bf, one_bf};

  // pre-hoisted LDS offsets (shorts); dt=1 adds 2048 ((32+l31)&7 == l31&7)
  const int ak0 = (l31 << 4) + (h32 << 3);
  const int ak1 = ((32 + l31) << 4) + (h32 << 3);
  const int rb0 = l31 << 6;
  const int sw0 = l31 & 7;
  const int v00 = rb0 + (((0 + h32) ^ sw0) << 3);  // c=0, pair 0
  const int v01 = rb0 + (((2 + h32) ^ sw0) << 3);  // c=0, pair 1
  const int v10 = rb0 + (((4 + h32) ^ sw0) << 3);  // c=1, pair 0
  const int v11 = rb0 + (((6 + h32) ^ sw0) << 3);  // c=1, pair 1

  auto stage = [&](int kt, int sel) {
    const int j0 = kt << 6;
    // K tile: 64 keys x 16 kdims, linear dest = tid*16 B. Waves 0-1 only
    // (wave-uniform branch -> waves 0-1 issue 3 VMEM/stage, waves 2-3 two).
    if (tid < 128) {
      int kr = j0 + (tid >> 1);
      if (kr >= SP_) kr = 0;  // clamp; masked via p=0 in tail chunk
      gl_lds16(K + ((size_t)(kbase + kr) << 8) + hoff + ((tid & 1) << 3),
               &ksb[sel][tid << 3]);
    }
    // V tile: 64 d-rows x 64 keys; dest linear, source inverse-swizzled so
    // stored granule g' holds keys (g'^(d&7))*8.. -> conflict-even b128 reads
#pragma unroll
    for (int pp = 0; pp < 2; ++pp) {
      const int gi = (pp << 8) + tid;
      const int d  = gi >> 3;
      int koff = j0 + (((gi & 7) ^ (d & 7)) << 3);
      if (koff > SP_ - 8) koff = SP_ - 8;  // tail clamp (data masked by p=0)
      gl_lds16(VT + (size_t)(vbase + d) * SP_ + koff, &vsb[sel][gi << 3]);
    }
  };

  auto chunk = [&](int c, bool tail8, int sel) {
    // A-frag: K[key = c*32 + l31][kd = 8*h32 + j]
    const short8 ak = *(const short8*)&ksb[sel][c ? ak1 : ak0];
    // sc[r] = S^T[key = crow(r,h32)][q = l31]
    floatx16 sc = __builtin_amdgcn_mfma_f32_32x32x16_bf16(ak, aq, z16, 0, 0, 0);

    float p[16];
#pragma unroll
    for (int r = 0; r < 16; ++r) {
      float e = __builtin_amdgcn_exp2f(sc[r]);
      p[r] = (tail8 && r >= 8) ? 0.f : e;   // tail: crow>=16 invalid
    }

    // pack bf16 pairs; word m holds keys crow(2m..2m+1,h)
    const unsigned w0 = pk2(p[0], p[1]),   w1 = pk2(p[2], p[3]);
    const unsigned w2 = pk2(p[4], p[5]),   w3 = pk2(p[6], p[7]);
    const unsigned w4 = pk2(p[8], p[9]),   w5 = pk2(p[10], p[11]);
    const unsigned w6 = pk2(p[12], p[13]), w7 = pk2(p[14], p[15]);

    // permlane32_swap: out0 = {in0.lo | in1.lo->hi}, out1 = {in0.hi->lo | in1.hi}
    const uint2v a02 = __builtin_amdgcn_permlane32_swap(w0, w2, false, false);
    const uint2v a13 = __builtin_amdgcn_permlane32_swap(w1, w3, false, false);
    const uint2v a46 = __builtin_amdgcn_permlane32_swap(w4, w6, false, false);
    const uint2v a57 = __builtin_amdgcn_permlane32_swap(w5, w7, false, false);

    // PA frags: A[q = l31][key = kc*16 + 8*h32 + j]
    const short8 pa0 = __builtin_bit_cast(short8, (uintx4){a02[0], a13[0], a02[1], a13[1]});
    const short8 pa1 = __builtin_bit_cast(short8, (uintx4){a46[0], a57[0], a46[1], a57[1]});

    // row-sum on the MFMA pipe: C[q][*] = sum_k P[q][k] -- same C-layout as
    // Of, so the epilogue divides element-wise with ZERO cross-lane traffic.
    Ol = __builtin_amdgcn_mfma_f32_32x32x16_bf16(pa0, ones, Ol, 0, 0, 0);
    Ol = __builtin_amdgcn_mfma_f32_32x32x16_bf16(pa1, ones, Ol, 0, 0, 0);

    const int o0 = c ? v10 : v00;
    const int o1 = c ? v11 : v01;
    {
      const short8 bv0 = *(const short8*)&vsb[sel][o0];
      const short8 bv1 = *(const short8*)&vsb[sel][o1];
      Of0 = __builtin_amdgcn_mfma_f32_32x32x16_bf16(pa0, bv0, Of0, 0, 0, 0);
      Of0 = __builtin_amdgcn_mfma_f32_32x32x16_bf16(pa1, bv1, Of0, 0, 0, 0);
    }
    {
      const short8 bv0 = *(const short8*)&vsb[sel][o0 + 2048];
      const short8 bv1 = *(const short8*)&vsb[sel][o1 + 2048];
      Of1 = __builtin_amdgcn_mfma_f32_32x32x16_bf16(pa0, bv0, Of1, 0, 0, 0);
      Of1 = __builtin_amdgcn_mfma_f32_32x32x16_bf16(pa1, bv1, Of1, 0, 0, 0);
    }
  };

  // --- 3-deep pipeline with counted vmcnt. Invariant at barrier of tile kt:
  // stage(kt+1) complete, stage(kt+2) in flight. vmcnt counts per-WAVE VMEM
  // instructions: waves 0-1 issue 3 per stage, waves 2-3 issue 2.
  stage(0, 0);
  stage(1, 1);
  if (w < 2) asm volatile("s_waitcnt vmcnt(3)" ::: "memory");
  else       asm volatile("s_waitcnt vmcnt(2)" ::: "memory");
  __builtin_amdgcn_s_barrier();

  for (int kt = 0; kt < 32; ++kt) {
    const int sel = kt % 3;
    if (kt < 31) stage(kt + 2, (kt + 2) % 3);
    chunk(0, false, sel);
    chunk(1, false, sel);
    if (kt < 31) {
      if (w < 2) asm volatile("s_waitcnt vmcnt(3)" ::: "memory");
      else       asm volatile("s_waitcnt vmcnt(2)" ::: "memory");
    } else {
      asm volatile("s_waitcnt vmcnt(0)" ::: "memory");
    }
    __builtin_amdgcn_s_barrier();
  }
  chunk(0, true, 2);  // tail tile 32 (32 % 3 == 2; keys 2048..2063 valid)

  // epilogue: out[b][q][h*64 + d] = Of / Ol (all three share the C-layout)
#pragma unroll
  for (int r = 0; r < 16; ++r) {
    const int cr = (r & 3) + ((r >> 2) << 3) + (h32 << 2);  // crow(r,h32)
    const float invr = 1.f / Ol[r];
    const int qg = q0 + cr;
    float* op = out + (((size_t)(b * S_ + qg)) << 10) + (h << 6) + l31;
    op[0]  = Of0[r] * invr;
    op[32] = Of1[r] * invr;
  }
}

// ---------------------------------------------------------------------------
extern "C" void kernel_launch(void* const* d_in, const int* in_sizes, int n_in,
                              void* d_out, int out_size, void* d_ws, size_t ws_size,
                              hipStream_t stream) {
  (void)in_sizes; (void)n_in; (void)out_size; (void)ws_size;

  const float* x   = (const float*)d_in[0];
  const float* Wq  = (const float*)d_in[1];
  const float* bq  = (const float*)d_in[2];
  const float* Wqc = (const float*)d_in[3];
  const float* bqc = (const float*)d_in[4];
  const float* Wk  = (const float*)d_in[5];
  const float* bk  = (const float*)d_in[6];
  const float* Wkc = (const float*)d_in[7];
  const float* bkc = (const float*)d_in[8];
  const float* Wv  = (const float*)d_in[9];
  const float* bv  = (const float*)d_in[10];
  const float* Wvc = (const float*)d_in[11];
  const float* bvc = (const float*)d_in[12];
  float* out = (float*)d_out;

  // workspace layout (ushort units), total ~48 MB
  unsigned short* qb  = (unsigned short*)d_ws;
  unsigned short* kbf = qb  + (size_t)MTOT * 256;
  unsigned short* vt  = kbf + (size_t)MTOT * 256;
  unsigned short* xh  = vt  + (size_t)B_ * 1024 * SP_;
  unsigned short* wq2 = xh  + (size_t)B_ * S_ * D_;          // [2][256][1024]
  unsigned short* wk2 = wq2 + (size_t)2 * 256 * 1024;
  unsigned short* wv2 = wk2 + (size_t)2 * 256 * 1024;        // [2][1024][1024]

  dim3 blk(256);
  cast_x<<<(B_ * S_ * D_) / 1024, blk, 0, stream>>>(x, xh);

  wcast_all<<<dim3(96, 32), blk, 0, stream>>>(Wq, Wqc, Wk, Wkc, Wv, Wvc,
                                              wq2, wk2, wv2);

  // merged q+k+v CSS GEMM: grid.x 0-1 -> q (pre-scaled by QSCALE), 2-3 -> k,
  // 4-11 -> v (transposed VT output)
  css_mfma2<<<dim3(12, 65), blk, 0, stream>>>(xh, wq2, bq, bqc, wk2, bk, bkc,
                                              wv2, bv, bvc, qb, kbf, vt);

  attn_mfma<<<B_ * H_ * (S_ / 128), blk, 0, stream>>>(qb, kbf, vt, out);
}

// Round 7
// 242.556 us; speedup vs baseline: 1.4317x; 1.0351x over previous
//
#include <hip/hip_runtime.h>
#include <hip/hip_bf16.h>
#include <cstdint>

// Problem constants
#define B_   4
#define S_   2048
#define SP_  2064        // S + 16 pad rows (pad rows: x == 0 -> bias-only qkv)
#define D_   1024
#define H_   16
#define MTOT (B_ * SP_)  // 8256 rows

// q is pre-scaled by 0.125 * log2(e) so softmax = exp2(q'.k) directly
#define QSCALE 0.18033688011112042f

typedef __attribute__((ext_vector_type(8))) short short8;
typedef __attribute__((ext_vector_type(4))) float floatx4;
typedef __attribute__((ext_vector_type(16))) float floatx16;
typedef __attribute__((ext_vector_type(2))) unsigned int uint2v;
typedef __attribute__((ext_vector_type(4))) unsigned int uintx4;

// fp32 -> bf16 round-to-nearest-even
static __device__ inline unsigned short f2b(float f) {
  unsigned u = __builtin_bit_cast(unsigned, f);
  u += 0x7FFFu + ((u >> 16) & 1u);
  return (unsigned short)(u >> 16);
}

// pack two fp32 -> bf16x2 word. Compiler-known path (__float22bfloat162_rn
// lowers to v_cvt_pk_bf16_f32 with proper hazard handling). Do NOT use
// inline-asm cvt_pk here: asm def -> permlane tripped an unmodeled
// cross-lane hazard (R3 NaN). (__hip_bfloat162 is not trivially copyable ->
// memcpy, not bit_cast.)
static __device__ inline unsigned pk2(float a, float b) {
  __hip_bfloat162 h = __float22bfloat162_rn(make_float2(a, b));
  unsigned r;
  __builtin_memcpy(&r, &h, 4);   // a in low 16, b in high 16
  return r;
}

// async global->LDS, 16 B per lane, dest = wave-uniform base + lane*16
static __device__ inline void gl_lds16(const unsigned short* g, unsigned short* l) {
  __builtin_amdgcn_global_load_lds((__attribute__((address_space(1))) void*)(g),
                                   (__attribute__((address_space(3))) void*)(l),
                                   16, 0, 0);
}

// ---------------------------------------------------------------------------
// Merged pre-pass: cast x (fp32->bf16) + transpose/cast all six weights.
// grid (8192 + 3072): bx < 8192 -> cast_x tile; else wcast tile
// (decode: gx = (bx-8192)%96 selects weight+n0, (bx-8192)/96 selects k0).
// ---------------------------------------------------------------------------
__global__ __launch_bounds__(256) void prep(
    const float* __restrict__ x, unsigned short* __restrict__ xh,
    const float* __restrict__ Wq,  const float* __restrict__ Wqc,
    const float* __restrict__ Wk,  const float* __restrict__ Wkc,
    const float* __restrict__ Wv,  const float* __restrict__ Wvc,
    unsigned short* __restrict__ wq2, unsigned short* __restrict__ wk2,
    unsigned short* __restrict__ wv2)
{
  __shared__ float tl[32][33];
  const int t = threadIdx.x;
  int bx = blockIdx.x;

  if (bx < 8192) {           // ---- cast_x part
    const int idx = (bx * 256 + t) * 4;
    float4 v = *(const float4*)(x + idx);
    ushort4 h;
    h.x = f2b(v.x); h.y = f2b(v.y); h.z = f2b(v.z); h.w = f2b(v.w);
    *(ushort4*)(xh + idx) = h;
    return;
  }

  // ---- wcast part
  bx -= 8192;
  const int gx = bx % 96;
  const int k0 = (bx / 96) * 32;

  const float* W; unsigned short* T; int N, nx;
  if (gx < 8)       { W = Wq;  T = wq2;               nx = gx;      N = 256;  }
  else if (gx < 16) { W = Wqc; T = wq2 + 256 * 1024;  nx = gx - 8;  N = 256;  }
  else if (gx < 24) { W = Wk;  T = wk2;               nx = gx - 16; N = 256;  }
  else if (gx < 32) { W = Wkc; T = wk2 + 256 * 1024;  nx = gx - 24; N = 256;  }
  else if (gx < 64) { W = Wv;  T = wv2;               nx = gx - 32; N = 1024; }
  else              { W = Wvc; T = wv2 + 1024 * 1024; nx = gx - 64; N = 1024; }

  const int n0 = nx * 32;
  const int r  = t >> 3;
  const int c  = (t & 7) * 4;

  float4 w = *(const float4*)(W + (size_t)(k0 + r) * N + n0 + c);
  tl[r][c + 0] = w.x; tl[r][c + 1] = w.y; tl[r][c + 2] = w.z; tl[r][c + 3] = w.w;
  __syncthreads();

  ushort4 h;
  h.x = f2b(tl[c + 0][r]); h.y = f2b(tl[c + 1][r]);
  h.z = f2b(tl[c + 2][r]); h.w = f2b(tl[c + 3][r]);
  *(ushort4*)(T + (size_t)(n0 + r) * 1024 + k0 + c) = h;
}

// ---------------------------------------------------------------------------
// Merged CSS GEMM (q + k + v in ONE dispatch), v2:
//  * global_load_lds width=16 staging, T2 source-swizzled LDS (as R4).
//  * T3/T4: TRIPLE-buffered LDS + counted vmcnt. stage(kt+2) stays in
//    flight across the barrier (vmcnt(6) = one stage outstanding, all
//    waves issue 6 loads/stage); lgkmcnt(0) pins ds_reads before the raw
//    s_barrier. Full drain (vmcnt(0)) only at the last staged tile.
//  * T1: XCD-chunked bijective block swizzle (780 = 8*97+4, m204 formula):
//    consecutive wgids share one A-tile (12 nt's per m0) and land on ONE
//    XCD -> A-tile is L2-resident per XCD instead of re-fetched 8x.
//  * pad rows (grow % SP_ >= S_) stage dummy data (row 0) and get the exact
//    bias-only value scl*b*sigmoid(c) in the epilogue.
// LDS: 3 x 3 x [128][32] = 72 KiB -> 2 blocks/CU; epilogue Os[128][136]
// overlays buffer 0.
// ---------------------------------------------------------------------------
__global__ __launch_bounds__(256, 2) void css_mfma2(
    const unsigned short* __restrict__ xh,
    const unsigned short* __restrict__ wq2, const float* __restrict__ bq,
    const float* __restrict__ bqc,
    const unsigned short* __restrict__ wk2, const float* __restrict__ bk,
    const float* __restrict__ bkc,
    const unsigned short* __restrict__ wv2, const float* __restrict__ bv,
    const float* __restrict__ bvc,
    unsigned short* __restrict__ qb, unsigned short* __restrict__ kbf,
    unsigned short* __restrict__ vt)
{
  __shared__ __align__(16) unsigned short smem[36864];  // 73728 B (3 bufs)

  const int t = threadIdx.x;

  // T1 bijective chunked swizzle: hwid -> wgid so each XCD gets a contiguous
  // chunk of wgids. nwg = 780, q = 97, r = 4.
  const int hwid = blockIdx.y * 12 + blockIdx.x;
  const int xcd  = hwid & 7;
  const int idx  = hwid >> 3;
  const int wgid = (xcd < 4 ? xcd * 98 : 392 + (xcd - 4) * 97) + idx;
  const int nt = wgid % 12;
  const int m0 = (wgid / 12) << 7;

  const unsigned short* w2;
  const float *bias, *bisc;
  unsigned short* outp;
  float scl;
  int n0, N, mode;
  size_t mstride;
  if (nt < 2) {
    w2 = wq2; bias = bq; bisc = bqc; outp = qb; scl = QSCALE;
    n0 = nt << 7; N = 256; mode = 0; mstride = (size_t)256 * 1024;
  } else if (nt < 4) {
    w2 = wk2; bias = bk; bisc = bkc; outp = kbf; scl = 1.0f;
    n0 = (nt - 2) << 7; N = 256; mode = 0; mstride = (size_t)256 * 1024;
  } else {
    w2 = wv2; bias = bv; bisc = bvc; outp = vt; scl = 1.0f;
    n0 = (nt - 4) << 7; N = 1024; mode = 1; mstride = (size_t)1024 * 1024;
  }

  // --- staging source pointers (T2 source-swizzle, as R4):
  // logical granule g = (t&3) ^ ((row>>1)&3), row = t>>2.
  const int ko_s = (((t & 3) ^ ((t >> 3) & 3)) << 3);  // swizzled col (shorts)

  const unsigned short* sA0;
  const unsigned short* sA1;
  {
    auto arow = [&](int row) -> const unsigned short* {
      const int grow = m0 + row;
      const int bb0 = grow / SP_;
      const int ss0 = grow - bb0 * SP_;
      const int r = (grow < MTOT && ss0 < S_) ? (bb0 * S_ + ss0) : 0;
      return xh + (size_t)r * D_ + ko_s;
    };
    sA0 = arow(t >> 2);
    sA1 = arow(64 + (t >> 2));
  }
  const int brow0 = t >> 2;
  const int brow1 = 64 + (t >> 2);
  const unsigned short* sB0 = w2 + (size_t)(n0 + brow0) * 1024 + ko_s;
  const unsigned short* sB1 = w2 + (size_t)(n0 + brow1) * 1024 + ko_s;
  const unsigned short* sG0 = sB0 + mstride;
  const unsigned short* sG1 = sB1 + mstride;

  const int lane = t & 63;
  const int w    = t >> 6;
  const int lo   = lane & 15;
  const int hi   = lane >> 4;
  const int wm   = (w & 1) << 6;
  const int wn   = (w >> 1) << 6;

  // fragment-read swizzle slot (loop-invariant): ((row>>1)&3)==((lo>>1)&3)
  const int sl8 = ((hi ^ ((lo >> 1) & 3)) << 3);

  floatx4 lin[4][4], gat[4][4];
#pragma unroll
  for (int i = 0; i < 4; ++i)
#pragma unroll
    for (int j = 0; j < 4; ++j) {
      lin[i][j] = (floatx4){0.f, 0.f, 0.f, 0.f};
      gat[i][j] = (floatx4){0.f, 0.f, 0.f, 0.f};
    }

  auto stage = [&](int kt, int sel) {
    const int k0 = kt << 5;
    unsigned short* dst = &smem[sel * 12288 + t * 8];   // 16 B per lane
    gl_lds16(sA0 + k0, dst);
    gl_lds16(sA1 + k0, dst + 2048);
    gl_lds16(sB0 + k0, dst + 4096);
    gl_lds16(sB1 + k0, dst + 6144);
    gl_lds16(sG0 + k0, dst + 8192);
    gl_lds16(sG1 + k0, dst + 10240);
  };

  // --- 3-deep pipeline, counted vmcnt (every wave issues 6 VMEM/stage).
  // Invariant at barrier of tile kt: stage(kt+1) complete, stage(kt+2) in
  // flight (vmcnt <= 6).
  stage(0, 0);
  stage(1, 1);
  asm volatile("s_waitcnt vmcnt(6)" ::: "memory");
  __builtin_amdgcn_s_barrier();

  for (int kt = 0; kt < 32; ++kt) {
    const int sel = kt % 3;
    if (kt < 30) stage(kt + 2, (kt + 2) % 3);

    const unsigned short* Ab = &smem[sel * 12288];
    short8 ah[4];
#pragma unroll
    for (int i = 0; i < 4; ++i)
      ah[i] = *(const short8*)(Ab + (wm + i * 16 + lo) * 32 + sl8);
#pragma unroll
    for (int j = 0; j < 4; ++j) {
      const int cb = (wn + j * 16 + lo) * 32 + sl8;
      short8 bh = *(const short8*)(Ab + 4096 + cb);
      short8 gh = *(const short8*)(Ab + 8192 + cb);
#pragma unroll
      for (int i = 0; i < 4; ++i) {
        lin[i][j] = __builtin_amdgcn_mfma_f32_16x16x32_bf16(ah[i], bh, lin[i][j], 0, 0, 0);
        gat[i][j] = __builtin_amdgcn_mfma_f32_16x16x32_bf16(ah[i], gh, gat[i][j], 0, 0, 0);
      }
    }

    // pin all ds_reads complete (data in VGPR), then allow one stage in
    // flight across the barrier; full drain only before the last tile.
    asm volatile("s_waitcnt lgkmcnt(0)" ::: "memory");
    if (kt < 30) asm volatile("s_waitcnt vmcnt(6)" ::: "memory");
    else         asm volatile("s_waitcnt vmcnt(0)" ::: "memory");
    __builtin_amdgcn_s_barrier();
  }

  // ---- epilogue: stage bf16 tile in LDS, then coalesced 16 B stores
  __syncthreads();  // compiler-visible barrier before Os overlays buffers
  unsigned short (*Os)[136] = reinterpret_cast<unsigned short (*)[136]>(&smem[0]);

#pragma unroll
  for (int j = 0; j < 4; ++j) {
    const int nl = wn + j * 16 + lo;
    const int n  = n0 + nl;
    const float bj = bias[n];
    const float cj = bisc[n];
#pragma unroll
    for (int i = 0; i < 4; ++i) {
      const int ml = wm + i * 16 + (hi << 2);
      unsigned short o16[4];
#pragma unroll
      for (int r = 0; r < 4; ++r) {
        const int gmr = m0 + ml + r;
        const int ssr = gmr - (gmr / SP_) * SP_;
        const bool padr = (ssr >= S_);          // x = 0 row -> bias-only
        float lv = (padr ? 0.f : lin[i][j][r]) + bj;
        float gv = (padr ? 0.f : gat[i][j][r]) + cj;
        o16[r] = f2b(scl * lv / (1.f + __expf(-gv)));
      }
      if (mode == 0) {
#pragma unroll
        for (int r = 0; r < 4; ++r) Os[ml + r][nl] = o16[r];
      } else {
        *(ushort4*)&Os[nl][ml] = make_ushort4(o16[0], o16[1], o16[2], o16[3]);
      }
    }
  }
  __syncthreads();

  // coalesced store: 16 consecutive lanes cover one 256 B row-run
#pragma unroll
  for (int c = 0; c < 8; ++c) {
    const int rr = (t >> 4) + 16 * c;   // Os row
    const int cc = (t & 15) << 3;       // Os col chunk (8 shorts = 16 B)
    uint4 val = *(const uint4*)&Os[rr][cc];
    if (mode == 0) {
      const int gm = m0 + rr;
      if (gm < MTOT)
        *(uint4*)(outp + (size_t)gm * N + n0 + cc) = val;
    } else {
      const int g = m0 + cc;            // 8-aligned; SP_ % 8 == 0 so no straddle
      if (g < MTOT) {
        const int vb = g / SP_;
        const int vs = g - vb * SP_;
        *(uint4*)(outp + (size_t)(vb * 1024 + n0 + rr) * SP_ + vs) = val;
      }
    }
  }
}

// ---------------------------------------------------------------------------
// MFMA flash attention v4 (R5-verified structure):
//  * T1 XCD swizzle, triple-buffered counted-vmcnt staging, swapped
//    32x32x16 QK^T, in-register softmax, ones-MFMA row-sum in C-layout.
//  * v5 delta: pk2 via __float22bfloat162_rn (1 VALU op vs 4).
// ---------------------------------------------------------------------------
__global__ __launch_bounds__(256, 4) void attn_mfma(
    const unsigned short* __restrict__ Q,   // bf16 [MTOT][256], pre-scaled
    const unsigned short* __restrict__ K,   // bf16 [MTOT][256]
    const unsigned short* __restrict__ VT,  // bf16 [B*1024][SP_]
    float* __restrict__ out)                // fp32 [B][S_][1024]
{
  // T1: HW round-robins consecutive blockIdx across XCDs; remap so each XCD
  // gets a contiguous 128-block chunk (= 8 (b,h) pairs). Bijective: 1024=8*128.
  const int bx = ((blockIdx.x & 7) << 7) + (blockIdx.x >> 3);
  const int qt = bx & 15;
  const int h  = (bx >> 4) & 15;
  const int b  = bx >> 8;

  const int tid  = threadIdx.x;
  const int lane = tid & 63;
  const int w    = tid >> 6;
  const int l31  = lane & 31;
  const int h32  = lane >> 5;

  const int kbase = b * SP_;        // row base into Q/K
  const int hoff  = h << 4;         // head col offset (shorts)
  const int vbase = (b << 10) + (h << 6);  // row base into VT
  const int q0    = (qt << 7) + (w << 5);  // this wave's first query

  __shared__ __align__(16) unsigned short ksb[3][64 * 16];  // [key][kdim]
  __shared__ __align__(16) unsigned short vsb[3][512 * 8];  // [d][granule^]

  // Q B-frag: B[kd = 8*h32 + j][q = l31]  (16 B contiguous per lane)
  const short8 aq =
      *(const short8*)(Q + ((size_t)(kbase + q0 + l31) << 8) + hoff + (h32 << 3));

  floatx16 z16;
#pragma unroll
  for (int r = 0; r < 16; ++r) z16[r] = 0.f;
  floatx16 Of0 = z16, Of1 = z16, Ol = z16;

  const short one_bf = (short)0x3F80;                 // bf16 1.0
  const short8 ones = {one_bf, one_bf, one_bf, one_bf,
                       one_bf, one_bf, one_bf, one_bf};

  // pre-hoisted LDS offsets (shorts); dt=1 adds 2048 ((32+l31)&7 == l31&7)
  const int ak0 = (l31 << 4) + (h32 << 3);
  const int ak1 = ((32 + l31) << 4) + (h32 << 3);
  const int rb0 = l31 << 6;
  const int sw0 = l31 & 7;
  const int v00 = rb0 + (((0 + h32) ^ sw0) << 3);  // c=0, pair 0
  const int v01 = rb0 + (((2 + h32) ^ sw0) << 3);  // c=0, pair 1
  const int v10 = rb0 + (((4 + h32) ^ sw0) << 3);  // c=1, pair 0
  const int v11 = rb0 + (((6 + h32) ^ sw0) << 3);  // c=1, pair 1

  auto stage = [&](int kt, int sel) {
    const int j0 = kt << 6;
    // K tile: 64 keys x 16 kdims, linear dest = tid*16 B. Waves 0-1 only
    // (wave-uniform branch -> waves 0-1 issue 3 VMEM/stage, waves 2-3 two).
    if (tid < 128) {
      int kr = j0 + (tid >> 1);
      if (kr >= SP_) kr = 0;  // clamp; masked via p=0 in tail chunk
      gl_lds16(K + ((size_t)(kbase + kr) << 8) + hoff + ((tid & 1) << 3),
               &ksb[sel][tid << 3]);
    }
    // V tile: 64 d-rows x 64 keys; dest linear, source inverse-swizzled so
    // stored granule g' holds keys (g'^(d&7))*8.. -> conflict-even b128 reads
#pragma unroll
    for (int pp = 0; pp < 2; ++pp) {
      const int gi = (pp << 8) + tid;
      const int d  = gi >> 3;
      int koff = j0 + (((gi & 7) ^ (d & 7)) << 3);
      if (koff > SP_ - 8) koff = SP_ - 8;  // tail clamp (data masked by p=0)
      gl_lds16(VT + (size_t)(vbase + d) * SP_ + koff, &vsb[sel][gi << 3]);
    }
  };

  auto chunk = [&](int c, bool tail8, int sel) {
    // A-frag: K[key = c*32 + l31][kd = 8*h32 + j]
    const short8 ak = *(const short8*)&ksb[sel][c ? ak1 : ak0];
    // sc[r] = S^T[key = crow(r,h32)][q = l31]
    floatx16 sc = __builtin_amdgcn_mfma_f32_32x32x16_bf16(ak, aq, z16, 0, 0, 0);

    float p[16];
#pragma unroll
    for (int r = 0; r < 16; ++r) {
      float e = __builtin_amdgcn_exp2f(sc[r]);
      p[r] = (tail8 && r >= 8) ? 0.f : e;   // tail: crow>=16 invalid
    }

    // pack bf16 pairs (v_cvt_pk_bf16_f32); word m holds keys crow(2m..2m+1,h)
    const unsigned w0 = pk2(p[0], p[1]),   w1 = pk2(p[2], p[3]);
    const unsigned w2 = pk2(p[4], p[5]),   w3 = pk2(p[6], p[7]);
    const unsigned w4 = pk2(p[8], p[9]),   w5 = pk2(p[10], p[11]);
    const unsigned w6 = pk2(p[12], p[13]), w7 = pk2(p[14], p[15]);

    // permlane32_swap: out0 = {in0.lo | in1.lo->hi}, out1 = {in0.hi->lo | in1.hi}
    const uint2v a02 = __builtin_amdgcn_permlane32_swap(w0, w2, false, false);
    const uint2v a13 = __builtin_amdgcn_permlane32_swap(w1, w3, false, false);
    const uint2v a46 = __builtin_amdgcn_permlane32_swap(w4, w6, false, false);
    const uint2v a57 = __builtin_amdgcn_permlane32_swap(w5, w7, false, false);

    // PA frags: A[q = l31][key = kc*16 + 8*h32 + j]
    const short8 pa0 = __builtin_bit_cast(short8, (uintx4){a02[0], a13[0], a02[1], a13[1]});
    const short8 pa1 = __builtin_bit_cast(short8, (uintx4){a46[0], a57[0], a46[1], a57[1]});

    // row-sum on the MFMA pipe: C[q][*] = sum_k P[q][k] -- same C-layout as
    // Of, so the epilogue divides element-wise with ZERO cross-lane traffic.
    Ol = __builtin_amdgcn_mfma_f32_32x32x16_bf16(pa0, ones, Ol, 0, 0, 0);
    Ol = __builtin_amdgcn_mfma_f32_32x32x16_bf16(pa1, ones, Ol, 0, 0, 0);

    const int o0 = c ? v10 : v00;
    const int o1 = c ? v11 : v01;
    {
      const short8 bv0 = *(const short8*)&vsb[sel][o0];
      const short8 bv1 = *(const short8*)&vsb[sel][o1];
      Of0 = __builtin_amdgcn_mfma_f32_32x32x16_bf16(pa0, bv0, Of0, 0, 0, 0);
      Of0 = __builtin_amdgcn_mfma_f32_32x32x16_bf16(pa1, bv1, Of0, 0, 0, 0);
    }
    {
      const short8 bv0 = *(const short8*)&vsb[sel][o0 + 2048];
      const short8 bv1 = *(const short8*)&vsb[sel][o1 + 2048];
      Of1 = __builtin_amdgcn_mfma_f32_32x32x16_bf16(pa0, bv0, Of1, 0, 0, 0);
      Of1 = __builtin_amdgcn_mfma_f32_32x32x16_bf16(pa1, bv1, Of1, 0, 0, 0);
    }
  };

  // --- 3-deep pipeline with counted vmcnt. Invariant at barrier of tile kt:
  // stage(kt+1) complete, stage(kt+2) in flight. vmcnt counts per-WAVE VMEM
  // instructions: waves 0-1 issue 3 per stage, waves 2-3 issue 2.
  stage(0, 0);
  stage(1, 1);
  if (w < 2) asm volatile("s_waitcnt vmcnt(3)" ::: "memory");
  else       asm volatile("s_waitcnt vmcnt(2)" ::: "memory");
  __builtin_amdgcn_s_barrier();

  for (int kt = 0; kt < 32; ++kt) {
    const int sel = kt % 3;
    if (kt < 31) stage(kt + 2, (kt + 2) % 3);
    chunk(0, false, sel);
    chunk(1, false, sel);
    if (kt < 31) {
      if (w < 2) asm volatile("s_waitcnt vmcnt(3)" ::: "memory");
      else       asm volatile("s_waitcnt vmcnt(2)" ::: "memory");
    } else {
      asm volatile("s_waitcnt vmcnt(0)" ::: "memory");
    }
    __builtin_amdgcn_s_barrier();
  }
  chunk(0, true, 2);  // tail tile 32 (32 % 3 == 2; keys 2048..2063 valid)

  // epilogue: out[b][q][h*64 + d] = Of / Ol (all three share the C-layout)
#pragma unroll
  for (int r = 0; r < 16; ++r) {
    const int cr = (r & 3) + ((r >> 2) << 3) + (h32 << 2);  // crow(r,h32)
    const float invr = 1.f / Ol[r];
    const int qg = q0 + cr;
    float* op = out + (((size_t)(b * S_ + qg)) << 10) + (h << 6) + l31;
    op[0]  = Of0[r] * invr;
    op[32] = Of1[r] * invr;
  }
}

// ---------------------------------------------------------------------------
extern "C" void kernel_launch(void* const* d_in, const int* in_sizes, int n_in,
                              void* d_out, int out_size, void* d_ws, size_t ws_size,
                              hipStream_t stream) {
  (void)in_sizes; (void)n_in; (void)out_size; (void)ws_size;

  const float* x   = (const float*)d_in[0];
  const float* Wq  = (const float*)d_in[1];
  const float* bq  = (const float*)d_in[2];
  const float* Wqc = (const float*)d_in[3];
  const float* bqc = (const float*)d_in[4];
  const float* Wk  = (const float*)d_in[5];
  const float* bk  = (const float*)d_in[6];
  const float* Wkc = (const float*)d_in[7];
  const float* bkc = (const float*)d_in[8];
  const float* Wv  = (const float*)d_in[9];
  const float* bv  = (const float*)d_in[10];
  const float* Wvc = (const float*)d_in[11];
  const float* bvc = (const float*)d_in[12];
  float* out = (float*)d_out;

  // workspace layout (ushort units), total ~48 MB
  unsigned short* qb  = (unsigned short*)d_ws;
  unsigned short* kbf = qb  + (size_t)MTOT * 256;
  unsigned short* vt  = kbf + (size_t)MTOT * 256;
  unsigned short* xh  = vt  + (size_t)B_ * 1024 * SP_;
  unsigned short* wq2 = xh  + (size_t)B_ * S_ * D_;          // [2][256][1024]
  unsigned short* wk2 = wq2 + (size_t)2 * 256 * 1024;
  unsigned short* wv2 = wk2 + (size_t)2 * 256 * 1024;        // [2][1024][1024]

  dim3 blk(256);

  // merged cast_x + weight transpose (one dispatch)
  prep<<<dim3(8192 + 3072), blk, 0, stream>>>(x, xh, Wq, Wqc, Wk, Wkc, Wv, Wvc,
                                              wq2, wk2, wv2);

  // merged q+k+v CSS GEMM: nt 0-1 -> q (pre-scaled by QSCALE), 2-3 -> k,
  // 4-11 -> v (transposed VT output)
  css_mfma2<<<dim3(12, 65), blk, 0, stream>>>(xh, wq2, bq, bqc, wk2, bk, bkc,
                                              wv2, bv, bvc, qb, kbf, vt);

  attn_mfma<<<B_ * H_ * (S_ / 128), blk, 0, stream>>>(qb, kbf, vt, out);
}